// Round 8
// baseline (277.524 us; speedup 1.0000x reference)
//
#include <hip/hip_runtime.h>
#include <hip/hip_bf16.h>
#include <math.h>

// Problem constants (setup_inputs: B=4, T=1024)
#define BB 4
#define TT 1024
#define BT 4096

// Workspace layout (fp32 offsets in floats)
#define OFF_BLOCKS 0          // [BT][64]  blocks in [i*4+e] channel order
#define OFF_QKVB   262144     // [16][BT][12] per-block qkv (dead after k_blk_part)
#define OFF_RECVP  262144     // [B][128 src][1024 k] recv partials (aliases QKVB, 2 MB)
#define OFF_ALLB   1048576    // [BT][64]  per-block MHA output (all_blocks)
#define OFF_QKVC   1310720    // [BT][192] cross qkv
#define OFF_LC     2097152    // [B*8][T]  cross softmax denominators (unnormalized)
#define OFF_ACCC   2129920    // [B*8][T][8] cross PV (normalized by l)
#define OFF_RECV   2392064    // [B][T]    attention-received column means
#define OFF_LN1    2396160    // [BT][64]  post-LN1 activations
#define WS_FLOATS  2658320

__device__ inline float rcpf(float x) { return __builtin_amdgcn_rcpf(x); }

// ---------- in-block dtype detection (wave-uniform, all waves agree) ----------
__device__ inline bool detect_bf16(const void* M) {
  const unsigned short* h = (const unsigned short*)M;
  unsigned short v = h[threadIdx.x & 63];
  int e = (v >> 7) & 0xff;
  unsigned long long m = __ballot((e >= 90) && (e <= 141));
  return __popcll(m) >= 58;
}

// ---------- dtype-templated load helpers (single path per instantiation) ----------
template <bool ISBF>
__device__ inline float ldf(const void* p, int i) {
  if (ISBF) return __bfloat162float(((const __hip_bfloat16*)p)[i]);
  else      return ((const float*)p)[i];
}

template <bool ISBF>
__device__ inline void load8(const void* p, int off, float* w) {
  if (ISBF) {
    uint4 u = *reinterpret_cast<const uint4*>((const __hip_bfloat16*)p + off);
    w[0] = __uint_as_float(u.x << 16); w[1] = __uint_as_float(u.x & 0xffff0000u);
    w[2] = __uint_as_float(u.y << 16); w[3] = __uint_as_float(u.y & 0xffff0000u);
    w[4] = __uint_as_float(u.z << 16); w[5] = __uint_as_float(u.z & 0xffff0000u);
    w[6] = __uint_as_float(u.w << 16); w[7] = __uint_as_float(u.w & 0xffff0000u);
  } else {
    const float4* f = (const float4*)((const float*)p + off);
    float4 a = f[0], b = f[1];
    w[0]=a.x; w[1]=a.y; w[2]=a.z; w[3]=a.w; w[4]=b.x; w[5]=b.y; w[6]=b.z; w[7]=b.w;
  }
}

template <bool ISBF>
__device__ inline float dot8(const void* W, int off, const float* x) {
  float w[8]; load8<ISBF>(W, off, w);
  return w[0]*x[0] + w[1]*x[1] + w[2]*x[2] + w[3]*x[3]
       + w[4]*x[4] + w[5]*x[5] + w[6]*x[6] + w[7]*x[7];
}

// ---------- K1: blocks gather + per-block QKV ----------
template <bool ISBF>
__global__ void __launch_bounds__(256) k_prep(
    const void* __restrict__ M,
    const void* __restrict__ Wqkv_blk,
    const void* __restrict__ bqkv_blk,
    float* __restrict__ blocks, float* __restrict__ qkv_blk) {
  if (detect_bf16(M) != ISBF) return;
  int g = blockIdx.x * 256 + threadIdx.x;        // 65536 = 16 blocks * 4096 tokens
  int i = g >> 12, bt = g & 4095;
  int rb = i >> 2, cb = i & 3;
  float x[4];
  #pragma unroll
  for (int r = 0; r < 2; ++r)
    #pragma unroll
    for (int c = 0; c < 2; ++c)
      x[r*2+c] = ldf<ISBF>(M, bt*64 + (rb*2+r)*8 + cb*2 + c);
  float* bo = blocks + bt*64 + i*4;
  #pragma unroll
  for (int j = 0; j < 4; ++j) bo[j] = x[j];
  float* o = qkv_blk + (i*BT + bt) * 12;
  #pragma unroll
  for (int c = 0; c < 12; ++c) {
    float a = ldf<ISBF>(bqkv_blk, i*12 + c);
    #pragma unroll
    for (int j = 0; j < 4; ++j) a += ldf<ISBF>(Wqkv_blk, i*48 + c*4 + j) * x[j];
    o[c] = a;
  }
}

// ---------- K2: per-block attention, 8-wave key-split, 2 queries/thread ----------
template <bool ISBF>
__global__ void __launch_bounds__(512) k_blk_part(
    const void* __restrict__ M,
    const float* __restrict__ qkv_blk,
    const void* __restrict__ Wo_blk,
    const void* __restrict__ bo_blk,
    float* __restrict__ all_blocks) {
  if (detect_bf16(M) != ISBF) return;
  __shared__ float red[128*49];      // [qrow][wv*6+c], stride 49 (odd -> conflict-free)
  int bid = blockIdx.x;              // grid 512 = 16i * 4b * 8qt
  int qt = bid & 7, b = (bid >> 3) & 3, i = bid >> 5;
  int tid = threadIdx.x;
  int wv = __builtin_amdgcn_readfirstlane(tid) >> 6;   // wave id 0..7 in SGPR
  int ql = tid & 63;
  const float* base = qkv_blk + (size_t)(i*BT + b*TT) * 12;
  int qa = qt*128 + ql, qb = qa + 64;
  const float* qra = base + qa*12;
  const float* qrb = base + qb*12;
  const float S2 = 0.70710678f;      // 1/sqrt(Dh=2)
  float qa00 = qra[0]*S2, qa01 = qra[1]*S2, qa10 = qra[2]*S2, qa11 = qra[3]*S2;
  float qb00 = qrb[0]*S2, qb01 = qrb[1]*S2, qb10 = qrb[2]*S2, qb11 = qrb[3]*S2;
  float la0=0.f, la1=0.f, aa00=0.f, aa01=0.f, aa10=0.f, aa11=0.f;
  float lb0=0.f, lb1=0.f, ab00=0.f, ab01=0.f, ab10=0.f, ab11=0.f;
  int kbeg = wv*128;
  #pragma unroll 4
  for (int k = kbeg; k < kbeg + 128; ++k) {
    const float* kr = base + k*12 + 4;    // uniform address -> s_load_dwordx8
    float k0=kr[0], k1=kr[1], k2=kr[2], k3=kr[3];
    float v0=kr[4], v1=kr[5], v2=kr[6], v3=kr[7];
    float pa0 = __expf(qa00*k0 + qa01*k1);
    float pa1 = __expf(qa10*k2 + qa11*k3);
    float pb0 = __expf(qb00*k0 + qb01*k1);
    float pb1 = __expf(qb10*k2 + qb11*k3);
    la0 += pa0; aa00 += pa0*v0; aa01 += pa0*v1;
    la1 += pa1; aa10 += pa1*v2; aa11 += pa1*v3;
    lb0 += pb0; ab00 += pb0*v0; ab01 += pb0*v1;
    lb1 += pb1; ab10 += pb1*v2; ab11 += pb1*v3;
  }
  float* ra = red + ql*49 + wv*6;
  ra[0]=la0; ra[1]=la1; ra[2]=aa00; ra[3]=aa01; ra[4]=aa10; ra[5]=aa11;
  float* rb = red + (ql+64)*49 + wv*6;
  rb[0]=lb0; rb[1]=lb1; rb[2]=ab00; rb[3]=ab01; rb[4]=ab10; rb[5]=ab11;
  __syncthreads();
  if (tid < 128) {
    float s[6] = {0.f,0.f,0.f,0.f,0.f,0.f};
    #pragma unroll
    for (int w = 0; w < 8; ++w) {
      const float* p = red + tid*49 + w*6;
      #pragma unroll
      for (int c = 0; c < 6; ++c) s[c] += p[c];
    }
    float r0 = rcpf(s[0]), r1 = rcpf(s[1]);
    float o[4] = { s[2]*r0, s[3]*r0, s[4]*r1, s[5]*r1 };
    int q2 = qt*128 + tid;
    float* outp = all_blocks + (size_t)(b*TT + q2)*64 + i*4;
    #pragma unroll
    for (int j = 0; j < 4; ++j) {
      float a = ldf<ISBF>(bo_blk, i*4 + j);
      #pragma unroll
      for (int m2 = 0; m2 < 4; ++m2) a += ldf<ISBF>(Wo_blk, i*16 + j*4 + m2) * o[m2];
      outp[j] = a;
    }
  }
}

// ---------- K3: cross QKV projection (64 -> 192) ----------
template <bool ISBF>
__global__ void __launch_bounds__(256) k_qkv_c(
    const void* __restrict__ M,
    const float* __restrict__ all_blocks,
    const void* __restrict__ Wqkv_c,
    const void* __restrict__ bqkv_c,
    float* __restrict__ qkv_c) {
  if (detect_bf16(M) != ISBF) return;
  __shared__ float xs[8*64];
  int t0 = blockIdx.x * 8;         // grid 512
  for (int idx = threadIdx.x; idx < 512; idx += 256)
    xs[idx] = all_blocks[t0*64 + idx];
  __syncthreads();
  int tok = threadIdx.x >> 5, lane32 = threadIdx.x & 31;
  const float* x = xs + tok*64;
  #pragma unroll
  for (int kk = 0; kk < 6; ++kk) {
    int c = kk*32 + lane32;
    float a = ldf<ISBF>(bqkv_c, c);
    #pragma unroll
    for (int j = 0; j < 64; j += 8) a += dot8<ISBF>(Wqkv_c, c*64 + j, x + j);
    qkv_c[(t0 + tok)*192 + c] = a;
  }
}

// ---------- K4: cross attention, 8-wave key-split, 2 queries/thread ----------
__global__ void __launch_bounds__(512) k_cross4(
    const float* __restrict__ qkv_c,
    float* __restrict__ l_c, float* __restrict__ acc_c) {
  __shared__ float red[128*73];      // [qrow][wv*9+c], stride 73 (odd -> conflict-free)
  int bid = blockIdx.x;              // grid 256 = 4b * 8h * 8qt
  int qt = bid & 7, h = (bid >> 3) & 7, b = bid >> 6;
  int tid = threadIdx.x;
  int wv = __builtin_amdgcn_readfirstlane(tid) >> 6;
  int ql = tid & 63;
  const float* base = qkv_c + (size_t)b*TT*192;
  int qa = qt*128 + ql, qb = qa + 64;
  float qva[8], qvb[8];
  #pragma unroll
  for (int c = 0; c < 8; ++c) {
    qva[c] = base[qa*192 + h*8 + c] * 0.35355339f;   // 1/sqrt(8)
    qvb[c] = base[qb*192 + h*8 + c] * 0.35355339f;
  }
  float la = 0.f, lb = 0.f, aca[8], acb[8];
  #pragma unroll
  for (int c = 0; c < 8; ++c) { aca[c] = 0.f; acb[c] = 0.f; }
  int kbeg = wv*128;
  #pragma unroll 2
  for (int k = kbeg; k < kbeg + 128; ++k) {
    const float* kr = base + (size_t)k*192 + 64  + h*8;  // K chans: uniform -> s_load
    const float* vr = base + (size_t)k*192 + 128 + h*8;  // V chans: uniform -> s_load
    float sa = 0.f, sb = 0.f;
    #pragma unroll
    for (int c = 0; c < 8; ++c) { sa += qva[c] * kr[c]; sb += qvb[c] * kr[c]; }
    float pa = __expf(sa), pb = __expf(sb);
    la += pa; lb += pb;
    #pragma unroll
    for (int c = 0; c < 8; ++c) { aca[c] += pa * vr[c]; acb[c] += pb * vr[c]; }
  }
  float* ra = red + ql*73 + wv*9;
  ra[0] = la;
  #pragma unroll
  for (int c = 0; c < 8; ++c) ra[1+c] = aca[c];
  float* rb = red + (ql+64)*73 + wv*9;
  rb[0] = lb;
  #pragma unroll
  for (int c = 0; c < 8; ++c) rb[1+c] = acb[c];
  __syncthreads();
  if (tid < 128) {
    float ls = 0.f, as[8];
    #pragma unroll
    for (int c = 0; c < 8; ++c) as[c] = 0.f;
    #pragma unroll
    for (int w = 0; w < 8; ++w) {
      const float* p = red + tid*73 + w*9;
      ls += p[0];
      #pragma unroll
      for (int c = 0; c < 8; ++c) as[c] += p[1+c];
    }
    float invl = rcpf(ls);
    int q2 = qt*128 + tid;
    int idx = (b*8 + h)*TT + q2;
    l_c[idx] = ls;
    #pragma unroll
    for (int c = 0; c < 8; ++c) acc_c[idx*8 + c] = as[c] * invl;   // normalized PV
  }
}

// ---------- K5: Wo_c projection on normalized PV, residual, LN1 ----------
template <bool ISBF>
__global__ void __launch_bounds__(256) k_finalize_cross(
    const void* __restrict__ M,
    const float* __restrict__ all_blocks,
    const float* __restrict__ acc_c,
    const void* __restrict__ Wo_c, const void* __restrict__ bo_c,
    const void* __restrict__ g1, const void* __restrict__ be1,
    float* __restrict__ ln1) {
  if (detect_bf16(M) != ISBF) return;
  __shared__ float pvs[4*64];
  int tt = threadIdx.x >> 6, j = threadIdx.x & 63;  // one token per wave, lane = channel
  int t = blockIdx.x*4 + tt;       // grid 1024
  int b = t >> 10, tl = t & 1023;
  int h = j >> 3;
  int idx = (b*8 + h)*TT + tl;
  pvs[tt*64 + j] = acc_c[idx*8 + (j & 7)];
  __syncthreads();
  float a = ldf<ISBF>(bo_c, j);
  const float* p = pvs + tt*64;
  #pragma unroll
  for (int m = 0; m < 64; m += 8) a += dot8<ISBF>(Wo_c, j*64 + m, p + m);
  float x = all_blocks[t*64 + j] + a;
  float s = x, s2 = x*x;
  #pragma unroll
  for (int off = 32; off; off >>= 1) { s += __shfl_xor(s, off); s2 += __shfl_xor(s2, off); }
  float mu  = s  * (1.f/64.f);
  float var = s2 * (1.f/64.f) - mu*mu;
  float y = (x - mu) * rsqrtf(var + 1e-5f) * ldf<ISBF>(g1, j) + ldf<ISBF>(be1, j);
  ln1[t*64 + j] = y;
}

// ---------- K6: recv — thread owns 4 keys, write-once coalesced partials ----------
__global__ void __launch_bounds__(64) k_recv_t4(
    const float* __restrict__ qkv_c,
    const float* __restrict__ l_c,
    float* __restrict__ recv_part) {
  int bid = blockIdx.x;              // grid 2048 = 4b * 8h * 4kt * 16qs
  int qs = bid & 15, kt = (bid >> 4) & 3, h = (bid >> 6) & 7, b = bid >> 9;
  const float* base = qkv_c + (size_t)b*TT*192;
  const float* lrow = l_c + (b*8 + h)*TT;
  int ql = threadIdx.x;
  float kv[4][8];
  #pragma unroll
  for (int i = 0; i < 4; ++i) {
    int k = kt*256 + i*64 + ql;
    #pragma unroll
    for (int c = 0; c < 8; ++c)
      kv[i][c] = base[(size_t)k*192 + 64 + h*8 + c] * 0.35355339f;
  }
  float acc[4] = {0.f, 0.f, 0.f, 0.f};
  #pragma unroll 2
  for (int qq = 0; qq < 64; ++qq) {
    int q = qs*64 + qq;
    const float* qr = base + (size_t)q*192 + h*8;   // uniform -> s_load
    float q0=qr[0],q1=qr[1],q2=qr[2],q3=qr[3],q4=qr[4],q5=qr[5],q6=qr[6],q7=qr[7];
    float invl = rcpf(lrow[q]);                     // uniform load + rcp
    #pragma unroll
    for (int i = 0; i < 4; ++i) {
      float s = q0*kv[i][0] + q1*kv[i][1] + q2*kv[i][2] + q3*kv[i][3]
              + q4*kv[i][4] + q5*kv[i][5] + q6*kv[i][6] + q7*kv[i][7];
      acc[i] += __expf(s) * invl;
    }
  }
  // layout [b][src][k]: lanes store consecutive k -> coalesced; every slot written once
  float* rp = recv_part + ((size_t)(b*128 + h*16 + qs)) * 1024;
  #pragma unroll
  for (int i = 0; i < 4; ++i) rp[kt*256 + i*64 + ql] = acc[i];
}

// ---------- K6b: reduce 128 src partials -> attn_recv ----------
__global__ void __launch_bounds__(256) k_recv_reduce(
    const float* __restrict__ recv_part, float* __restrict__ attn_recv) {
  int g = blockIdx.x * 256 + threadIdx.x;   // 4096 = b*1024+k
  int b = g >> 10, k = g & 1023;
  const float* p = recv_part + (size_t)b*128*1024 + k;
  float s = 0.f;
  #pragma unroll 8
  for (int src = 0; src < 128; ++src) s += p[(size_t)src*1024];  // lanes coalesced per src
  attn_recv[g] = s * (1.f/8192.f);          // /(H=8 * T=1024)
}

// ---------- K7: FFN + LN2 + sensitivity gate + un-blocking to 8x8 ----------
template <bool ISBF>
__global__ void __launch_bounds__(256) k_ffn_out(
    const void* __restrict__ M,
    const float* __restrict__ ln1,
    const void* __restrict__ W1b, const void* __restrict__ b1b,
    const void* __restrict__ W2b, const void* __restrict__ b2b,
    const void* __restrict__ g2, const void* __restrict__ be2,
    const float* __restrict__ blocks,
    const int* __restrict__ tok32,
    const float* __restrict__ attn_recv,
    const void* __restrict__ sens_emb,
    const void* __restrict__ sens_alpha,
    void* __restrict__ out) {
  if (detect_bf16(M) != ISBF) return;
  __shared__ float ld[4*64];
  __shared__ float hbuf[4*256];
  int t0 = blockIdx.x * 4;         // grid 1024, 4 tokens per WG
  ld[threadIdx.x] = ln1[t0*64 + threadIdx.x];
  __syncthreads();
  {
    float acc[4];
    float bb = ldf<ISBF>(b1b, threadIdx.x);
    #pragma unroll
    for (int tt = 0; tt < 4; ++tt) acc[tt] = bb;
    #pragma unroll
    for (int j = 0; j < 64; j += 8) {
      float w[8]; load8<ISBF>(W1b, threadIdx.x*64 + j, w);
      #pragma unroll
      for (int jj = 0; jj < 8; ++jj)
        #pragma unroll
        for (int tt = 0; tt < 4; ++tt) acc[tt] += w[jj] * ld[tt*64 + j + jj];
    }
    #pragma unroll
    for (int tt = 0; tt < 4; ++tt) {
      float v = acc[tt];
      // tanh-GELU in sigmoid form: v * sigmoid(1.5957691*v + 0.07135481*v^3)
      float u = 1.5957691f*v + 0.07135481f*v*v*v;
      hbuf[tt*256 + threadIdx.x] = v * rcpf(1.f + __expf(-u));
    }
  }
  __syncthreads();
  int tt = threadIdx.x >> 6, j = threadIdx.x & 63;   // token per wave, lane = channel
  int t = t0 + tt, b = t >> 10, tl = t & 1023;
  float y = ldf<ISBF>(b2b, j);
  const float* hb = hbuf + tt*256;
  #pragma unroll
  for (int k = 0; k < 256; k += 8) y += dot8<ISBF>(W2b, j*256 + k, hb + k);
  float z = ld[tt*64 + j] + y;
  float s = z, s2 = z*z;
  #pragma unroll
  for (int off = 32; off; off >>= 1) { s += __shfl_xor(s, off); s2 += __shfl_xor(s2, off); }
  float mu  = s  * (1.f/64.f);
  float var = s2 * (1.f/64.f) - mu*mu;
  float y2 = (z - mu) * rsqrtf(var + 1e-5f) * ldf<ISBF>(g2, j) + ldf<ISBF>(be2, j);
  bool is64 = ((tok32[1] | tok32[3] | tok32[5] | tok32[7]) == 0);
  int tok = is64 ? tok32[t*2] : tok32[t];
  int i = j >> 2, e = j & 3;
  float recv = attn_recv[b*TT + tl];
  float sv = ldf<ISBF>(sens_emb, tok*16 + i) + recv * ldf<ISBF>(sens_alpha, i);
  float sg = rcpf(1.f + __expf(-sv));
  float blk = blocks[t*64 + j];
  float nb = blk + (y2 - blk) * sg;
  int rb = i >> 2, cb = i & 3, r = e >> 1, c = e & 1;
  int oidx = t*64 + (rb*2 + r)*8 + cb*2 + c;
  if (ISBF) ((__hip_bfloat16*)out)[oidx] = __float2bfloat16(nb);
  else      ((float*)out)[oidx] = nb;
}

extern "C" void kernel_launch(void* const* d_in, const int* in_sizes, int n_in,
                              void* d_out, int out_size, void* d_ws, size_t ws_size,
                              hipStream_t stream) {
  const void* M        = d_in[0];
  const int*  tok      = (const int*)d_in[1];
  const void* Wqkv_blk = d_in[2];
  const void* bqkv_blk = d_in[3];
  const void* Wo_blk   = d_in[4];
  const void* bo_blk   = d_in[5];
  const void* Wqkv_c   = d_in[6];
  const void* bqkv_c   = d_in[7];
  const void* Wo_c     = d_in[8];
  const void* bo_c     = d_in[9];
  const void* W1       = d_in[10];
  const void* b1       = d_in[11];
  const void* W2       = d_in[12];
  const void* b2       = d_in[13];
  const void* g1       = d_in[14];
  const void* be1      = d_in[15];
  const void* g2i      = d_in[16];
  const void* be2      = d_in[17];
  const void* sens_emb = d_in[18];
  const void* sens_al  = d_in[19];

  float* ws = (float*)d_ws;
  float* blocks    = ws + OFF_BLOCKS;
  float* qkv_blk   = ws + OFF_QKVB;
  float* recv_part = ws + OFF_RECVP;   // aliases qkv_blk (dead after k_blk_part)
  float* all_blk   = ws + OFF_ALLB;
  float* qkv_c     = ws + OFF_QKVC;
  float* l_c       = ws + OFF_LC;
  float* acc_c     = ws + OFF_ACCC;
  float* attn_recv = ws + OFF_RECV;
  float* ln1       = ws + OFF_LN1;

  k_prep<true ><<<256, 256, 0, stream>>>(M, Wqkv_blk, bqkv_blk, blocks, qkv_blk);
  k_prep<false><<<256, 256, 0, stream>>>(M, Wqkv_blk, bqkv_blk, blocks, qkv_blk);
  k_blk_part<true ><<<512, 512, 0, stream>>>(M, qkv_blk, Wo_blk, bo_blk, all_blk);
  k_blk_part<false><<<512, 512, 0, stream>>>(M, qkv_blk, Wo_blk, bo_blk, all_blk);
  k_qkv_c<true ><<<512, 256, 0, stream>>>(M, all_blk, Wqkv_c, bqkv_c, qkv_c);
  k_qkv_c<false><<<512, 256, 0, stream>>>(M, all_blk, Wqkv_c, bqkv_c, qkv_c);
  k_cross4<<<256, 512, 0, stream>>>(qkv_c, l_c, acc_c);
  k_finalize_cross<true ><<<1024, 256, 0, stream>>>(M, all_blk, acc_c, Wo_c, bo_c, g1, be1, ln1);
  k_finalize_cross<false><<<1024, 256, 0, stream>>>(M, all_blk, acc_c, Wo_c, bo_c, g1, be1, ln1);
  k_recv_t4<<<2048, 64, 0, stream>>>(qkv_c, l_c, recv_part);
  k_recv_reduce<<<16, 256, 0, stream>>>(recv_part, attn_recv);
  k_ffn_out<true ><<<1024, 256, 0, stream>>>(M, ln1, W1, b1, W2, b2, g2i, be2,
                                             blocks, tok, attn_recv, sens_emb, sens_al,
                                             (void*)d_out);
  k_ffn_out<false><<<1024, 256, 0, stream>>>(M, ln1, W1, b1, W2, b2, g2i, be2,
                                             blocks, tok, attn_recv, sens_emb, sens_al,
                                             (void*)d_out);
}

// Round 10
// 269.927 us; speedup vs baseline: 1.0281x; 1.0281x over previous
//
#include <hip/hip_runtime.h>
#include <hip/hip_bf16.h>
#include <math.h>

// Problem constants (setup_inputs: B=4, T=1024)
#define BB 4
#define TT 1024
#define BT 4096

// Workspace layout (fp32 offsets in floats)
#define OFF_BLOCKS 0          // [BT][64]  blocks in [i*4+e] channel order
#define OFF_QKVB   262144     // [16][BT][12] per-block qkv (dead after k_blk_part)
#define OFF_RECVP  262144     // [B][128 src][1024 k] recv partials (aliases QKVB, 2 MB)
#define OFF_ALLB   1048576    // [BT][64]  per-block MHA output (all_blocks)
#define OFF_QKVC   1310720    // [BT][192] cross qkv
#define OFF_LC     2097152    // [B*8][T]  cross softmax denominators (unnormalized)
#define OFF_ACCC   2129920    // [B*8][T][8] cross PV (normalized by l)
#define OFF_LN1    2396160    // [BT][64]  post-LN1 activations
#define WS_FLOATS  2658320

__device__ inline float rcpf(float x) { return __builtin_amdgcn_rcpf(x); }

// ---------- in-block dtype detection (wave-uniform, all waves agree) ----------
// bf16 buffers: all 64 halfwords have exponent-field in [90,141] -> popcnt 64.
// fp32 buffers: even halfwords are low-mantissa bits (~20% pass) -> popcnt ~38.
__device__ inline bool detect_bf16(const void* M) {
  const unsigned short* h = (const unsigned short*)M;
  unsigned short v = h[threadIdx.x & 63];
  int e = (v >> 7) & 0xff;
  unsigned long long m = __ballot((e >= 90) && (e <= 141));
  return __popcll(m) >= 58;
}

// ---------- dtype-templated load helpers (single path per instantiation) ----------
template <bool ISBF>
__device__ inline float ldf(const void* p, int i) {
  if (ISBF) return __bfloat162float(((const __hip_bfloat16*)p)[i]);
  else      return ((const float*)p)[i];
}

template <bool ISBF>
__device__ inline void load8(const void* p, int off, float* w) {
  if (ISBF) {
    uint4 u = *reinterpret_cast<const uint4*>((const __hip_bfloat16*)p + off);
    w[0] = __uint_as_float(u.x << 16); w[1] = __uint_as_float(u.x & 0xffff0000u);
    w[2] = __uint_as_float(u.y << 16); w[3] = __uint_as_float(u.y & 0xffff0000u);
    w[4] = __uint_as_float(u.z << 16); w[5] = __uint_as_float(u.z & 0xffff0000u);
    w[6] = __uint_as_float(u.w << 16); w[7] = __uint_as_float(u.w & 0xffff0000u);
  } else {
    const float4* f = (const float4*)((const float*)p + off);
    float4 a = f[0], b = f[1];
    w[0]=a.x; w[1]=a.y; w[2]=a.z; w[3]=a.w; w[4]=b.x; w[5]=b.y; w[6]=b.z; w[7]=b.w;
  }
}

template <bool ISBF>
__device__ inline float dot8(const void* W, int off, const float* x) {
  float w[8]; load8<ISBF>(W, off, w);
  return w[0]*x[0] + w[1]*x[1] + w[2]*x[2] + w[3]*x[3]
       + w[4]*x[4] + w[5]*x[5] + w[6]*x[6] + w[7]*x[7];
}

// ---------- K1: blocks gather + per-block QKV ----------
template <bool ISBF>
__global__ void __launch_bounds__(256) k_prep(
    const void* __restrict__ M,
    const void* __restrict__ Wqkv_blk,
    const void* __restrict__ bqkv_blk,
    float* __restrict__ blocks, float* __restrict__ qkv_blk) {
  if (detect_bf16(M) != ISBF) return;
  int g = blockIdx.x * 256 + threadIdx.x;        // 65536 = 16 blocks * 4096 tokens
  int i = g >> 12, bt = g & 4095;
  int rb = i >> 2, cb = i & 3;
  float x[4];
  #pragma unroll
  for (int r = 0; r < 2; ++r)
    #pragma unroll
    for (int c = 0; c < 2; ++c)
      x[r*2+c] = ldf<ISBF>(M, bt*64 + (rb*2+r)*8 + cb*2 + c);
  float* bo = blocks + bt*64 + i*4;
  #pragma unroll
  for (int j = 0; j < 4; ++j) bo[j] = x[j];
  float* o = qkv_blk + (i*BT + bt) * 12;
  #pragma unroll
  for (int c = 0; c < 12; ++c) {
    float a = ldf<ISBF>(bqkv_blk, i*12 + c);
    #pragma unroll
    for (int j = 0; j < 4; ++j) a += ldf<ISBF>(Wqkv_blk, i*48 + c*4 + j) * x[j];
    o[c] = a;
  }
}

// ---------- K2: per-block attention, 8-wave key-split, 2 queries/thread ----------
template <bool ISBF>
__global__ void __launch_bounds__(512) k_blk_part(
    const void* __restrict__ M,
    const float* __restrict__ qkv_blk,
    const void* __restrict__ Wo_blk,
    const void* __restrict__ bo_blk,
    float* __restrict__ all_blocks) {
  if (detect_bf16(M) != ISBF) return;
  __shared__ float red[128*49];      // [qrow][wv*6+c], stride 49 (odd -> conflict-free)
  int bid = blockIdx.x;              // grid 512 = 16i * 4b * 8qt
  int qt = bid & 7, b = (bid >> 3) & 3, i = bid >> 5;
  int tid = threadIdx.x;
  int wv = __builtin_amdgcn_readfirstlane(tid) >> 6;   // wave id 0..7 in SGPR
  int ql = tid & 63;
  const float* base = qkv_blk + (size_t)(i*BT + b*TT) * 12;
  int qa = qt*128 + ql, qb = qa + 64;
  const float* qra = base + qa*12;
  const float* qrb = base + qb*12;
  const float S2 = 0.70710678f;      // 1/sqrt(Dh=2)
  float qa00 = qra[0]*S2, qa01 = qra[1]*S2, qa10 = qra[2]*S2, qa11 = qra[3]*S2;
  float qb00 = qrb[0]*S2, qb01 = qrb[1]*S2, qb10 = qrb[2]*S2, qb11 = qrb[3]*S2;
  float la0=0.f, la1=0.f, aa00=0.f, aa01=0.f, aa10=0.f, aa11=0.f;
  float lb0=0.f, lb1=0.f, ab00=0.f, ab01=0.f, ab10=0.f, ab11=0.f;
  int kbeg = wv*128;
  #pragma unroll 4
  for (int k = kbeg; k < kbeg + 128; ++k) {
    const float* kr = base + k*12 + 4;    // uniform address -> s_load_dwordx8
    float k0=kr[0], k1=kr[1], k2=kr[2], k3=kr[3];
    float v0=kr[4], v1=kr[5], v2=kr[6], v3=kr[7];
    float pa0 = __expf(qa00*k0 + qa01*k1);
    float pa1 = __expf(qa10*k2 + qa11*k3);
    float pb0 = __expf(qb00*k0 + qb01*k1);
    float pb1 = __expf(qb10*k2 + qb11*k3);
    la0 += pa0; aa00 += pa0*v0; aa01 += pa0*v1;
    la1 += pa1; aa10 += pa1*v2; aa11 += pa1*v3;
    lb0 += pb0; ab00 += pb0*v0; ab01 += pb0*v1;
    lb1 += pb1; ab10 += pb1*v2; ab11 += pb1*v3;
  }
  float* ra = red + ql*49 + wv*6;
  ra[0]=la0; ra[1]=la1; ra[2]=aa00; ra[3]=aa01; ra[4]=aa10; ra[5]=aa11;
  float* rb = red + (ql+64)*49 + wv*6;
  rb[0]=lb0; rb[1]=lb1; rb[2]=ab00; rb[3]=ab01; rb[4]=ab10; rb[5]=ab11;
  __syncthreads();
  if (tid < 128) {
    float s[6] = {0.f,0.f,0.f,0.f,0.f,0.f};
    #pragma unroll
    for (int w = 0; w < 8; ++w) {
      const float* p = red + tid*49 + w*6;
      #pragma unroll
      for (int c = 0; c < 6; ++c) s[c] += p[c];
    }
    float r0 = rcpf(s[0]), r1 = rcpf(s[1]);
    float o[4] = { s[2]*r0, s[3]*r0, s[4]*r1, s[5]*r1 };
    int q2 = qt*128 + tid;
    float* outp = all_blocks + (size_t)(b*TT + q2)*64 + i*4;
    #pragma unroll
    for (int j = 0; j < 4; ++j) {
      float a = ldf<ISBF>(bo_blk, i*4 + j);
      #pragma unroll
      for (int m2 = 0; m2 < 4; ++m2) a += ldf<ISBF>(Wo_blk, i*16 + j*4 + m2) * o[m2];
      outp[j] = a;
    }
  }
}

// ---------- K3: cross QKV projection (64 -> 192) ----------
template <bool ISBF>
__global__ void __launch_bounds__(256) k_qkv_c(
    const void* __restrict__ M,
    const float* __restrict__ all_blocks,
    const void* __restrict__ Wqkv_c,
    const void* __restrict__ bqkv_c,
    float* __restrict__ qkv_c) {
  if (detect_bf16(M) != ISBF) return;
  __shared__ float xs[8*64];
  int t0 = blockIdx.x * 8;         // grid 512
  for (int idx = threadIdx.x; idx < 512; idx += 256)
    xs[idx] = all_blocks[t0*64 + idx];
  __syncthreads();
  int tok = threadIdx.x >> 5, lane32 = threadIdx.x & 31;
  const float* x = xs + tok*64;
  #pragma unroll
  for (int kk = 0; kk < 6; ++kk) {
    int c = kk*32 + lane32;
    float a = ldf<ISBF>(bqkv_c, c);
    #pragma unroll
    for (int j = 0; j < 64; j += 8) a += dot8<ISBF>(Wqkv_c, c*64 + j, x + j);
    qkv_c[(t0 + tok)*192 + c] = a;
  }
}

// ---------- K4: cross attention, 8-wave key-split, 2 queries/thread (dtype-free) ----------
__global__ void __launch_bounds__(512) k_cross4(
    const float* __restrict__ qkv_c,
    float* __restrict__ l_c, float* __restrict__ acc_c) {
  __shared__ float red[128*73];      // [qrow][wv*9+c], stride 73 (odd -> conflict-free)
  int bid = blockIdx.x;              // grid 256 = 4b * 8h * 8qt
  int qt = bid & 7, h = (bid >> 3) & 7, b = bid >> 6;
  int tid = threadIdx.x;
  int wv = __builtin_amdgcn_readfirstlane(tid) >> 6;
  int ql = tid & 63;
  const float* base = qkv_c + (size_t)b*TT*192;
  int qa = qt*128 + ql, qb = qa + 64;
  float qva[8], qvb[8];
  #pragma unroll
  for (int c = 0; c < 8; ++c) {
    qva[c] = base[qa*192 + h*8 + c] * 0.35355339f;   // 1/sqrt(8)
    qvb[c] = base[qb*192 + h*8 + c] * 0.35355339f;
  }
  float la = 0.f, lb = 0.f, aca[8], acb[8];
  #pragma unroll
  for (int c = 0; c < 8; ++c) { aca[c] = 0.f; acb[c] = 0.f; }
  int kbeg = wv*128;
  #pragma unroll 2
  for (int k = kbeg; k < kbeg + 128; ++k) {
    const float* kr = base + (size_t)k*192 + 64  + h*8;  // K chans: uniform -> s_load
    const float* vr = base + (size_t)k*192 + 128 + h*8;  // V chans: uniform -> s_load
    float sa = 0.f, sb = 0.f;
    #pragma unroll
    for (int c = 0; c < 8; ++c) { sa += qva[c] * kr[c]; sb += qvb[c] * kr[c]; }
    float pa = __expf(sa), pb = __expf(sb);
    la += pa; lb += pb;
    #pragma unroll
    for (int c = 0; c < 8; ++c) { aca[c] += pa * vr[c]; acb[c] += pb * vr[c]; }
  }
  float* ra = red + ql*73 + wv*9;
  ra[0] = la;
  #pragma unroll
  for (int c = 0; c < 8; ++c) ra[1+c] = aca[c];
  float* rb = red + (ql+64)*73 + wv*9;
  rb[0] = lb;
  #pragma unroll
  for (int c = 0; c < 8; ++c) rb[1+c] = acb[c];
  __syncthreads();
  if (tid < 128) {
    float ls = 0.f, as[8];
    #pragma unroll
    for (int c = 0; c < 8; ++c) as[c] = 0.f;
    #pragma unroll
    for (int w = 0; w < 8; ++w) {
      const float* p = red + tid*73 + w*9;
      ls += p[0];
      #pragma unroll
      for (int c = 0; c < 8; ++c) as[c] += p[1+c];
    }
    float invl = rcpf(ls);
    int q2 = qt*128 + tid;
    int idx = (b*8 + h)*TT + q2;
    l_c[idx] = ls;
    #pragma unroll
    for (int c = 0; c < 8; ++c) acc_c[idx*8 + c] = as[c] * invl;   // normalized PV
  }
}

// ---------- K5: horizontal fusion of finalize-cross (blocks 0..1023) and
//             recv partials (blocks 1024..1535, 4 waves = 4 tiles each) ----------
template <bool ISBF>
__global__ void __launch_bounds__(256) k_fin_recv(
    const void* __restrict__ M,
    const float* __restrict__ all_blocks,
    const float* __restrict__ acc_c,
    const void* __restrict__ Wo_c, const void* __restrict__ bo_c,
    const void* __restrict__ g1, const void* __restrict__ be1,
    const float* __restrict__ qkv_c,
    const float* __restrict__ l_c,
    float* __restrict__ ln1,
    float* __restrict__ recv_part) {
  if (detect_bf16(M) != ISBF) return;
  __shared__ float pvs[4*64];
  if (blockIdx.x < 1024) {
    // --- finalize: Wo_c projection on normalized PV, residual, LN1 ---
    int tt = threadIdx.x >> 6, j = threadIdx.x & 63;  // token per wave, lane = channel
    int t = blockIdx.x*4 + tt;
    int b = t >> 10, tl = t & 1023;
    int h = j >> 3;
    int idx = (b*8 + h)*TT + tl;
    pvs[tt*64 + j] = acc_c[idx*8 + (j & 7)];
    __syncthreads();
    float a = ldf<ISBF>(bo_c, j);
    const float* p = pvs + tt*64;
    #pragma unroll
    for (int m = 0; m < 64; m += 8) a += dot8<ISBF>(Wo_c, j*64 + m, p + m);
    float x = all_blocks[t*64 + j] + a;
    float s = x, s2 = x*x;
    #pragma unroll
    for (int off = 32; off; off >>= 1) { s += __shfl_xor(s, off); s2 += __shfl_xor(s2, off); }
    float mu  = s  * (1.f/64.f);
    float var = s2 * (1.f/64.f) - mu*mu;
    float y = (x - mu) * rsqrtf(var + 1e-5f) * ldf<ISBF>(g1, j) + ldf<ISBF>(be1, j);
    ln1[t*64 + j] = y;
  } else {
    // --- recv: each wave = one (b,h,kt,qs) tile; thread owns 4 keys, write-once ---
    int ob = (blockIdx.x - 1024)*4 + (threadIdx.x >> 6);  // 0..2047
    int ql = threadIdx.x & 63;
    int qs = ob & 15, kt = (ob >> 4) & 3, h = (ob >> 6) & 7, b = ob >> 9;
    const float* base = qkv_c + (size_t)b*TT*192;
    const float* lrow = l_c + (b*8 + h)*TT;
    float kv[4][8];
    #pragma unroll
    for (int i = 0; i < 4; ++i) {
      int k = kt*256 + i*64 + ql;
      #pragma unroll
      for (int c = 0; c < 8; ++c)
        kv[i][c] = base[(size_t)k*192 + 64 + h*8 + c] * 0.35355339f;
    }
    float acc[4] = {0.f, 0.f, 0.f, 0.f};
    #pragma unroll 2
    for (int qq = 0; qq < 64; ++qq) {
      int q = qs*64 + qq;
      const float* qr = base + (size_t)q*192 + h*8;   // uniform -> s_load
      float q0=qr[0],q1=qr[1],q2=qr[2],q3=qr[3],q4=qr[4],q5=qr[5],q6=qr[6],q7=qr[7];
      float invl = rcpf(lrow[q]);                     // uniform load + rcp
      #pragma unroll
      for (int i = 0; i < 4; ++i) {
        float s = q0*kv[i][0] + q1*kv[i][1] + q2*kv[i][2] + q3*kv[i][3]
                + q4*kv[i][4] + q5*kv[i][5] + q6*kv[i][6] + q7*kv[i][7];
        acc[i] += __expf(s) * invl;
      }
    }
    // layout [b][src][k]: lanes store consecutive k -> coalesced; every slot written once
    float* rp = recv_part + ((size_t)(b*128 + h*16 + qs)) * 1024;
    #pragma unroll
    for (int i = 0; i < 4; ++i) rp[kt*256 + i*64 + ql] = acc[i];
  }
}

// ---------- K6: FFN + LN2 + fused recv-reduce + sensitivity gate + un-blocking ----------
template <bool ISBF>
__global__ void __launch_bounds__(256) k_ffn_out(
    const void* __restrict__ M,
    const float* __restrict__ ln1,
    const void* __restrict__ W1b, const void* __restrict__ b1b,
    const void* __restrict__ W2b, const void* __restrict__ b2b,
    const void* __restrict__ g2, const void* __restrict__ be2,
    const float* __restrict__ blocks,
    const int* __restrict__ tok32,
    const float* __restrict__ recv_part,
    const void* __restrict__ sens_emb,
    const void* __restrict__ sens_alpha,
    void* __restrict__ out) {
  if (detect_bf16(M) != ISBF) return;
  __shared__ float ld[4*64];
  __shared__ float hbuf[4*256];
  int t0 = blockIdx.x * 4;         // grid 1024, 4 tokens per WG
  ld[threadIdx.x] = ln1[t0*64 + threadIdx.x];
  // fused recv reduce: wave tt sums 128 partials for its token (lane = src, 2 each)
  int tt = threadIdx.x >> 6, lane = threadIdx.x & 63;
  float recv;
  {
    int t = t0 + tt, b = t >> 10, k = t & 1023;
    const float* rp = recv_part + (size_t)b*128*1024 + k;
    float s = rp[(size_t)lane*1024] + rp[(size_t)(lane+64)*1024];
    #pragma unroll
    for (int off = 32; off; off >>= 1) s += __shfl_xor(s, off);
    recv = s * (1.f/8192.f);       // /(H=8 * T=1024)
  }
  __syncthreads();
  {
    float acc[4];
    float bb = ldf<ISBF>(b1b, threadIdx.x);
    #pragma unroll
    for (int t2 = 0; t2 < 4; ++t2) acc[t2] = bb;
    #pragma unroll
    for (int j = 0; j < 64; j += 8) {
      float w[8]; load8<ISBF>(W1b, threadIdx.x*64 + j, w);
      #pragma unroll
      for (int jj = 0; jj < 8; ++jj)
        #pragma unroll
        for (int t2 = 0; t2 < 4; ++t2) acc[t2] += w[jj] * ld[t2*64 + j + jj];
    }
    #pragma unroll
    for (int t2 = 0; t2 < 4; ++t2) {
      float v = acc[t2];
      // tanh-GELU in sigmoid form: v * sigmoid(1.5957691*v + 0.07135481*v^3)
      float u = 1.5957691f*v + 0.07135481f*v*v*v;
      hbuf[t2*256 + threadIdx.x] = v * rcpf(1.f + __expf(-u));
    }
  }
  __syncthreads();
  int j = lane;                    // token per wave, lane = channel
  int t = t0 + tt, b = t >> 10;
  float y = ldf<ISBF>(b2b, j);
  const float* hb = hbuf + tt*256;
  #pragma unroll
  for (int k = 0; k < 256; k += 8) y += dot8<ISBF>(W2b, j*256 + k, hb + k);
  float z = ld[tt*64 + j] + y;
  float s = z, s2 = z*z;
  #pragma unroll
  for (int off = 32; off; off >>= 1) { s += __shfl_xor(s, off); s2 += __shfl_xor(s2, off); }
  float mu  = s  * (1.f/64.f);
  float var = s2 * (1.f/64.f) - mu*mu;
  float y2 = (z - mu) * rsqrtf(var + 1e-5f) * ldf<ISBF>(g2, j) + ldf<ISBF>(be2, j);
  bool is64 = ((tok32[1] | tok32[3] | tok32[5] | tok32[7]) == 0);
  int tok = is64 ? tok32[t*2] : tok32[t];
  int i = j >> 2, e = j & 3;
  float sv = ldf<ISBF>(sens_emb, tok*16 + i) + recv * ldf<ISBF>(sens_alpha, i);
  float sg = rcpf(1.f + __expf(-sv));
  float blk = blocks[t*64 + j];
  float nb = blk + (y2 - blk) * sg;
  int rb = i >> 2, cb = i & 3, r = e >> 1, c = e & 1;
  int oidx = t*64 + (rb*2 + r)*8 + cb*2 + c;
  if (ISBF) ((__hip_bfloat16*)out)[oidx] = __float2bfloat16(nb);
  else      ((float*)out)[oidx] = nb;
}

extern "C" void kernel_launch(void* const* d_in, const int* in_sizes, int n_in,
                              void* d_out, int out_size, void* d_ws, size_t ws_size,
                              hipStream_t stream) {
  const void* M        = d_in[0];
  const int*  tok      = (const int*)d_in[1];
  const void* Wqkv_blk = d_in[2];
  const void* bqkv_blk = d_in[3];
  const void* Wo_blk   = d_in[4];
  const void* bo_blk   = d_in[5];
  const void* Wqkv_c   = d_in[6];
  const void* bqkv_c   = d_in[7];
  const void* Wo_c     = d_in[8];
  const void* bo_c     = d_in[9];
  const void* W1       = d_in[10];
  const void* b1       = d_in[11];
  const void* W2       = d_in[12];
  const void* b2       = d_in[13];
  const void* g1       = d_in[14];
  const void* be1      = d_in[15];
  const void* g2i      = d_in[16];
  const void* be2      = d_in[17];
  const void* sens_emb = d_in[18];
  const void* sens_al  = d_in[19];

  float* ws = (float*)d_ws;
  float* blocks    = ws + OFF_BLOCKS;
  float* qkv_blk   = ws + OFF_QKVB;
  float* recv_part = ws + OFF_RECVP;   // aliases qkv_blk (dead after k_blk_part)
  float* all_blk   = ws + OFF_ALLB;
  float* qkv_c     = ws + OFF_QKVC;
  float* l_c       = ws + OFF_LC;
  float* acc_c     = ws + OFF_ACCC;
  float* ln1       = ws + OFF_LN1;

  k_prep<true ><<<256, 256, 0, stream>>>(M, Wqkv_blk, bqkv_blk, blocks, qkv_blk);
  k_prep<false><<<256, 256, 0, stream>>>(M, Wqkv_blk, bqkv_blk, blocks, qkv_blk);
  k_blk_part<true ><<<512, 512, 0, stream>>>(M, qkv_blk, Wo_blk, bo_blk, all_blk);
  k_blk_part<false><<<512, 512, 0, stream>>>(M, qkv_blk, Wo_blk, bo_blk, all_blk);
  k_qkv_c<true ><<<512, 256, 0, stream>>>(M, all_blk, Wqkv_c, bqkv_c, qkv_c);
  k_qkv_c<false><<<512, 256, 0, stream>>>(M, all_blk, Wqkv_c, bqkv_c, qkv_c);
  k_cross4<<<256, 512, 0, stream>>>(qkv_c, l_c, acc_c);
  k_fin_recv<true ><<<1536, 256, 0, stream>>>(M, all_blk, acc_c, Wo_c, bo_c, g1, be1,
                                              qkv_c, l_c, ln1, recv_part);
  k_fin_recv<false><<<1536, 256, 0, stream>>>(M, all_blk, acc_c, Wo_c, bo_c, g1, be1,
                                              qkv_c, l_c, ln1, recv_part);
  k_ffn_out<true ><<<1024, 256, 0, stream>>>(M, ln1, W1, b1, W2, b2, g2i, be2,
                                             blocks, tok, recv_part, sens_emb, sens_al,
                                             (void*)d_out);
  k_ffn_out<false><<<1024, 256, 0, stream>>>(M, ln1, W1, b1, W2, b2, g2i, be2,
                                             blocks, tok, recv_part, sens_emb, sens_al,
                                             (void*)d_out);
}

// Round 11
// 222.931 us; speedup vs baseline: 1.2449x; 1.2108x over previous
//
#include <hip/hip_runtime.h>
#include <hip/hip_bf16.h>
#include <math.h>

// Problem constants (setup_inputs: B=4, T=1024)
#define BB 4
#define TT 1024
#define BT 4096

// Workspace layout (fp32 offsets in floats)
#define OFF_BLOCKS 0          // [BT][64]  blocks in [i*4+e] channel order
#define OFF_QKVB   262144     // [16][BT][12] per-block qkv (dead after k_blk_part)
#define OFF_RECVP  262144     // [B][1024 k][128 src] recv partials (aliases QKVB, 2 MB)
#define OFF_ALLB   1048576    // [BT][64]  per-block MHA output (all_blocks)
#define OFF_QKVC   1310720    // [BT][192] cross qkv
#define OFF_LC     2097152    // [B*8][T]  cross softmax denominators
#define OFF_ACCC   2129920    // [B*8][T][8] cross PV (normalized by l)
#define OFF_LN1    2396160    // [BT][64]  post-LN1 activations
#define OFF_PARAMS 2658304    // repacked fp32 weights (see P_* below)
#define WS_FLOATS  2708624

// Param sub-offsets (floats, relative to OFF_PARAMS)
#define P_W1T    0        // [64 j][256 h]
#define P_W2T    16384    // [256 k][64 j]
#define P_WQCT   32768    // [64 j][192 c]
#define P_WOCT   45056    // [64 m][64 j]
#define P_WOBLK  49152    // [16 i][4 j][4 m]
#define P_BOBLK  49408
#define P_BQC    49472
#define P_BOC    49664
#define P_G1     49728
#define P_BE1    49792
#define P_B1     49856
#define P_B2     50112
#define P_G2     50176
#define P_BE2    50240
#define P_SAL    50304
#define P_TOTAL  50320

__device__ inline float rcpf(float x) { return __builtin_amdgcn_rcpf(x); }

// ---------- in-block dtype detection (wave-uniform) ----------
__device__ inline bool detect_bf16(const void* M) {
  const unsigned short* h = (const unsigned short*)M;
  unsigned short v = h[threadIdx.x & 63];
  int e = (v >> 7) & 0xff;
  unsigned long long m = __ballot((e >= 90) && (e <= 141));
  return __popcll(m) >= 58;
}

template <bool ISBF>
__device__ inline float ldf(const void* p, int i) {
  if (ISBF) return __bfloat162float(((const __hip_bfloat16*)p)[i]);
  else      return ((const float*)p)[i];
}

// ---------- K0: repack all weights to fp32 (transposed where consumers need it) ----------
template <bool ISBF>
__global__ void __launch_bounds__(256) k_repack(
    const void* __restrict__ M,
    const void* __restrict__ W1, const void* __restrict__ W2,
    const void* __restrict__ Wqkv_c, const void* __restrict__ Wo_c,
    const void* __restrict__ Wo_blk, const void* __restrict__ bo_blk,
    const void* __restrict__ bqkv_c, const void* __restrict__ bo_c,
    const void* __restrict__ g1, const void* __restrict__ be1,
    const void* __restrict__ b1, const void* __restrict__ b2,
    const void* __restrict__ g2, const void* __restrict__ be2,
    const void* __restrict__ sens_al,
    float* __restrict__ params) {
  if (detect_bf16(M) != ISBF) return;
  for (int o = blockIdx.x*256 + threadIdx.x; o < P_TOTAL; o += gridDim.x*256) {
    float v;
    if      (o < 16384) { int j = o >> 8, h2 = o & 255; v = ldf<ISBF>(W1, h2*64 + j); }
    else if (o < 32768) { int q = o - 16384; int k = q >> 6, j = q & 63; v = ldf<ISBF>(W2, j*256 + k); }
    else if (o < 45056) { int q = o - 32768; int j = q / 192, c = q % 192; v = ldf<ISBF>(Wqkv_c, c*64 + j); }
    else if (o < 49152) { int q = o - 45056; int m = q >> 6, j = q & 63; v = ldf<ISBF>(Wo_c, j*64 + m); }
    else if (o < 49408) v = ldf<ISBF>(Wo_blk, o - 49152);
    else if (o < 49472) v = ldf<ISBF>(bo_blk, o - 49408);
    else if (o < 49664) v = ldf<ISBF>(bqkv_c, o - 49472);
    else if (o < 49728) v = ldf<ISBF>(bo_c,   o - 49664);
    else if (o < 49792) v = ldf<ISBF>(g1,     o - 49728);
    else if (o < 49856) v = ldf<ISBF>(be1,    o - 49792);
    else if (o < 50112) v = ldf<ISBF>(b1,     o - 49856);
    else if (o < 50176) v = ldf<ISBF>(b2,     o - 50112);
    else if (o < 50240) v = ldf<ISBF>(g2,     o - 50176);
    else if (o < 50304) v = ldf<ISBF>(be2,    o - 50240);
    else                v = ldf<ISBF>(sens_al, o - 50304);
    params[o] = v;
  }
}

// ---------- K1: blocks gather + per-block QKV ----------
template <bool ISBF>
__global__ void __launch_bounds__(256) k_prep(
    const void* __restrict__ M,
    const void* __restrict__ Wqkv_blk,
    const void* __restrict__ bqkv_blk,
    float* __restrict__ blocks, float* __restrict__ qkv_blk) {
  if (detect_bf16(M) != ISBF) return;
  int g = blockIdx.x * 256 + threadIdx.x;        // 65536 = 16 blocks * 4096 tokens
  int i = g >> 12, bt = g & 4095;
  int rb = i >> 2, cb = i & 3;
  float x[4];
  #pragma unroll
  for (int r = 0; r < 2; ++r)
    #pragma unroll
    for (int c = 0; c < 2; ++c)
      x[r*2+c] = ldf<ISBF>(M, bt*64 + (rb*2+r)*8 + cb*2 + c);
  float* bo = blocks + bt*64 + i*4;
  #pragma unroll
  for (int j = 0; j < 4; ++j) bo[j] = x[j];
  float* o = qkv_blk + (i*BT + bt) * 12;
  #pragma unroll
  for (int c = 0; c < 12; ++c) {
    float a = ldf<ISBF>(bqkv_blk, i*12 + c);
    #pragma unroll
    for (int j = 0; j < 4; ++j) a += ldf<ISBF>(Wqkv_blk, i*48 + c*4 + j) * x[j];
    o[c] = a;
  }
}

// ---------- K2: per-block attention, LDS-staged K/V, 8-wave key-split, 2 q/thread ----------
__global__ void __launch_bounds__(512) k_blk_part(
    const float* __restrict__ qkv_blk,
    const float* __restrict__ params,
    float* __restrict__ all_blocks) {
  __shared__ float4 kv4[3072];       // 48 KB: the (i,b) slab [1024 rows][12 floats]
  __shared__ float red[128*49];      // stride 49 (odd -> conflict-free)
  float* kv = (float*)kv4;
  int bid = blockIdx.x;              // grid 512 = 16i * 4b * 8qt
  int qt = bid & 7, b = (bid >> 3) & 3, i = bid >> 5;
  int tid = threadIdx.x;
  int wv = __builtin_amdgcn_readfirstlane(tid) >> 6;
  int ql = tid & 63;
  const float4* slab = (const float4*)(qkv_blk + (size_t)(i*BT + b*TT) * 12);
  #pragma unroll
  for (int s = 0; s < 6; ++s) kv4[tid + s*512] = slab[tid + s*512];
  __syncthreads();
  int qa = qt*128 + ql, qb = qa + 64;
  const float* qra = kv + qa*12;
  const float* qrb = kv + qb*12;
  const float S2 = 0.70710678f;      // 1/sqrt(Dh=2)
  float qa00 = qra[0]*S2, qa01 = qra[1]*S2, qa10 = qra[2]*S2, qa11 = qra[3]*S2;
  float qb00 = qrb[0]*S2, qb01 = qrb[1]*S2, qb10 = qrb[2]*S2, qb11 = qrb[3]*S2;
  float la0=0.f, la1=0.f, aa00=0.f, aa01=0.f, aa10=0.f, aa11=0.f;
  float lb0=0.f, lb1=0.f, ab00=0.f, ab01=0.f, ab10=0.f, ab11=0.f;
  int kbeg = wv*128;
  #pragma unroll 4
  for (int k = kbeg; k < kbeg + 128; ++k) {
    const float* kr = kv + k*12 + 4;      // LDS broadcast (same addr all lanes)
    float k0=kr[0], k1=kr[1], k2=kr[2], k3=kr[3];
    float v0=kr[4], v1=kr[5], v2=kr[6], v3=kr[7];
    float pa0 = __expf(qa00*k0 + qa01*k1);
    float pa1 = __expf(qa10*k2 + qa11*k3);
    float pb0 = __expf(qb00*k0 + qb01*k1);
    float pb1 = __expf(qb10*k2 + qb11*k3);
    la0 += pa0; aa00 += pa0*v0; aa01 += pa0*v1;
    la1 += pa1; aa10 += pa1*v2; aa11 += pa1*v3;
    lb0 += pb0; ab00 += pb0*v0; ab01 += pb0*v1;
    lb1 += pb1; ab10 += pb1*v2; ab11 += pb1*v3;
  }
  float* ra = red + ql*49 + wv*6;
  ra[0]=la0; ra[1]=la1; ra[2]=aa00; ra[3]=aa01; ra[4]=aa10; ra[5]=aa11;
  float* rb = red + (ql+64)*49 + wv*6;
  rb[0]=lb0; rb[1]=lb1; rb[2]=ab00; rb[3]=ab01; rb[4]=ab10; rb[5]=ab11;
  __syncthreads();
  if (tid < 128) {
    float s[6] = {0.f,0.f,0.f,0.f,0.f,0.f};
    #pragma unroll
    for (int w = 0; w < 8; ++w) {
      const float* p = red + tid*49 + w*6;
      #pragma unroll
      for (int c = 0; c < 6; ++c) s[c] += p[c];
    }
    float r0 = rcpf(s[0]), r1 = rcpf(s[1]);
    float o[4] = { s[2]*r0, s[3]*r0, s[4]*r1, s[5]*r1 };
    int q2 = qt*128 + tid;
    const float* pWo = params + P_WOBLK + i*16;
    float* outp = all_blocks + (size_t)(b*TT + q2)*64 + i*4;
    #pragma unroll
    for (int j = 0; j < 4; ++j) {
      float a = params[P_BOBLK + i*4 + j];
      #pragma unroll
      for (int m2 = 0; m2 < 4; ++m2) a += pWo[j*4 + m2] * o[m2];
      outp[j] = a;
    }
  }
}

// ---------- K3: cross QKV projection, coalesced transposed weights ----------
__global__ void __launch_bounds__(256) k_qkv_c(
    const float* __restrict__ all_blocks,
    const float* __restrict__ params,
    float* __restrict__ qkv_c) {
  __shared__ float xs[4*64];
  int t0 = blockIdx.x * 4;           // grid 1024, wave per token
  xs[threadIdx.x] = all_blocks[t0*64 + threadIdx.x];
  __syncthreads();
  int tt = threadIdx.x >> 6, lane = threadIdx.x & 63;
  int t = t0 + tt;
  const float* x = xs + tt*64;
  const float* WT = params + P_WQCT;           // [j][192]
  float a0 = params[P_BQC + lane];
  float a1 = params[P_BQC + 64 + lane];
  float a2 = params[P_BQC + 128 + lane];
  #pragma unroll 8
  for (int j = 0; j < 64; ++j) {
    const float* r = WT + j*192;
    float xj = x[j];                           // LDS broadcast
    a0 += r[lane]       * xj;                  // coalesced 256 B
    a1 += r[64 + lane]  * xj;
    a2 += r[128 + lane] * xj;
  }
  float* o = qkv_c + (size_t)t*192;
  o[lane] = a0; o[64 + lane] = a1; o[128 + lane] = a2;
}

// ---------- K4: cross attention, 8-wave key-split, 1 q/thread, load rotation ----------
__global__ void __launch_bounds__(512) k_cross4(
    const float* __restrict__ qkv_c,
    float* __restrict__ l_c, float* __restrict__ acc_c) {
  __shared__ float red[64*73];       // stride 73 (odd -> conflict-free)
  int bid = blockIdx.x;              // grid 512 = 4b * 8h * 16qt
  int qt = bid & 15, h = (bid >> 4) & 7, b = bid >> 7;
  int tid = threadIdx.x;
  int wv = __builtin_amdgcn_readfirstlane(tid) >> 6;
  int ql = tid & 63;
  int h8 = h*8;
  const float* base = qkv_c + (size_t)b*TT*192;
  int q = qt*64 + ql;
  float qv[8];
  #pragma unroll
  for (int c = 0; c < 8; ++c) qv[c] = base[q*192 + h8 + c] * 0.35355339f; // 1/sqrt(8)
  float l = 0.f, acc[8];
  #pragma unroll
  for (int c = 0; c < 8; ++c) acc[c] = 0.f;
  int kbeg = wv*128;
  // software-pipelined: prefetch next K/V row while computing current
  float kb[8], vb[8];
  {
    const float* kp = base + (size_t)kbeg*192;
    #pragma unroll
    for (int c = 0; c < 8; ++c) { kb[c] = kp[64 + h8 + c]; vb[c] = kp[128 + h8 + c]; }
  }
  #pragma unroll 4
  for (int it = 0; it < 128; ++it) {
    const float* np = base + (size_t)(kbeg + ((it + 1) & 127))*192;  // wraps; last prefetch unused
    float kn[8], vn[8];
    #pragma unroll
    for (int c = 0; c < 8; ++c) { kn[c] = np[64 + h8 + c]; vn[c] = np[128 + h8 + c]; }
    float s = 0.f;
    #pragma unroll
    for (int c = 0; c < 8; ++c) s += qv[c] * kb[c];
    float p = __expf(s);
    l += p;
    #pragma unroll
    for (int c = 0; c < 8; ++c) acc[c] += p * vb[c];
    #pragma unroll
    for (int c = 0; c < 8; ++c) { kb[c] = kn[c]; vb[c] = vn[c]; }
  }
  float* rr = red + ql*73 + wv*9;
  rr[0] = l;
  #pragma unroll
  for (int c = 0; c < 8; ++c) rr[1+c] = acc[c];
  __syncthreads();
  if (tid < 64) {
    float ls = 0.f, as[8];
    #pragma unroll
    for (int c = 0; c < 8; ++c) as[c] = 0.f;
    #pragma unroll
    for (int w = 0; w < 8; ++w) {
      const float* p = red + tid*73 + w*9;
      ls += p[0];
      #pragma unroll
      for (int c = 0; c < 8; ++c) as[c] += p[1+c];
    }
    float invl = rcpf(ls);
    int q2 = qt*64 + tid;
    int idx = (b*8 + h)*TT + q2;
    l_c[idx] = ls;
    #pragma unroll
    for (int c = 0; c < 8; ++c) acc_c[idx*8 + c] = as[c] * invl;   // normalized PV
  }
}

// ---------- K5: fused finalize-cross (blocks 0..1023) + recv partials (1024..1535) ----------
__global__ void __launch_bounds__(256) k_fin_recv(
    const float* __restrict__ all_blocks,
    const float* __restrict__ acc_c,
    const float* __restrict__ params,
    const float* __restrict__ qkv_c,
    const float* __restrict__ l_c,
    float* __restrict__ ln1,
    float* __restrict__ recv_part) {
  __shared__ float pvs[4*64];
  int tt = threadIdx.x >> 6, lane = threadIdx.x & 63;
  if (blockIdx.x < 1024) {
    // finalize: Wo_c^T coalesced projection, residual, LN1
    int j = lane;
    int t = blockIdx.x*4 + tt;
    int b = t >> 10, tl = t & 1023;
    int h = j >> 3;
    int idx = (b*8 + h)*TT + tl;
    pvs[tt*64 + j] = acc_c[idx*8 + (j & 7)];
    __syncthreads();
    float a = params[P_BOC + j];
    const float* WoT = params + P_WOCT;        // [m][64]
    const float* p = pvs + tt*64;
    #pragma unroll 8
    for (int m = 0; m < 64; ++m) a += WoT[m*64 + j] * p[m];   // coalesced + broadcast
    float x = all_blocks[t*64 + j] + a;
    float s = x, s2 = x*x;
    #pragma unroll
    for (int off = 32; off; off >>= 1) { s += __shfl_xor(s, off); s2 += __shfl_xor(s2, off); }
    float mu  = s  * (1.f/64.f);
    float var = s2 * (1.f/64.f) - mu*mu;
    float y = (x - mu) * rsqrtf(var + 1e-5f) * params[P_G1 + j] + params[P_BE1 + j];
    ln1[t*64 + j] = y;
  } else {
    // recv: wave = one (b,h,kt,qs) tile; thread owns 4 keys; rotated q-loads
    int ob = (blockIdx.x - 1024)*4 + tt;       // 0..2047
    int ql = lane;
    int qs = ob & 15, kt = (ob >> 4) & 3, h = (ob >> 6) & 7, b = ob >> 9;
    int h8 = h*8;
    const float* base = qkv_c + (size_t)b*TT*192;
    const float* lrow = l_c + (b*8 + h)*TT;
    float kv[4][8];
    #pragma unroll
    for (int i = 0; i < 4; ++i) {
      int k = kt*256 + i*64 + ql;
      #pragma unroll
      for (int c = 0; c < 8; ++c)
        kv[i][c] = base[(size_t)k*192 + 64 + h8 + c] * 0.35355339f;
    }
    float acc[4] = {0.f, 0.f, 0.f, 0.f};
    float qb[8], lb;
    {
      const float* qr = base + (size_t)(qs*64)*192 + h8;
      #pragma unroll
      for (int c = 0; c < 8; ++c) qb[c] = qr[c];
      lb = lrow[qs*64];
    }
    #pragma unroll 2
    for (int qq = 0; qq < 64; ++qq) {
      int qn = qs*64 + ((qq + 1) & 63);
      const float* nr = base + (size_t)qn*192 + h8;
      float qn8[8];
      #pragma unroll
      for (int c = 0; c < 8; ++c) qn8[c] = nr[c];
      float ln = lrow[qn];
      float invl = rcpf(lb);
      #pragma unroll
      for (int i = 0; i < 4; ++i) {
        float s = qb[0]*kv[i][0] + qb[1]*kv[i][1] + qb[2]*kv[i][2] + qb[3]*kv[i][3]
                + qb[4]*kv[i][4] + qb[5]*kv[i][5] + qb[6]*kv[i][6] + qb[7]*kv[i][7];
        acc[i] += __expf(s) * invl;
      }
      #pragma unroll
      for (int c = 0; c < 8; ++c) qb[c] = qn8[c];
      lb = ln;
    }
    // layout [b][k][src]: reducer reads contiguous; writes scattered (4 stores/thread)
    int src = h*16 + qs;
    #pragma unroll
    for (int i = 0; i < 4; ++i) {
      int k = kt*256 + i*64 + ql;
      recv_part[((size_t)(b*1024 + k))*128 + src] = acc[i];
    }
  }
}

// ---------- K6: FFN + LN2 + fused recv-reduce + gate + un-blocking ----------
template <bool ISBF>
__global__ void __launch_bounds__(256) k_ffn_out(
    const void* __restrict__ M,
    const float* __restrict__ ln1,
    const float* __restrict__ params,
    const float* __restrict__ blocks,
    const int* __restrict__ tok32,
    const float* __restrict__ recv_part,
    const void* __restrict__ sens_emb,
    void* __restrict__ out) {
  if (detect_bf16(M) != ISBF) return;
  __shared__ float ld2[256];     // [j][tt]
  __shared__ float hbuf[1024];   // [tt][k]
  int t0 = blockIdx.x * 4;       // grid 1024, wave per token
  int tt = threadIdx.x >> 6, lane = threadIdx.x & 63;
  ld2[lane*4 + tt] = ln1[(t0 + tt)*64 + lane];
  // recv reduce: contiguous 512 B per token
  float recv;
  {
    int t = t0 + tt, b = t >> 10, k = t & 1023;
    const float* rp = recv_part + ((size_t)(b*1024 + k))*128;
    float s = rp[lane] + rp[lane + 64];
    #pragma unroll
    for (int off = 32; off; off >>= 1) s += __shfl_xor(s, off);
    recv = s * (1.f/8192.f);     // /(H=8 * T=1024)
  }
  __syncthreads();
  // phase 1: hidden = gelu(ln1 @ W1^T + b1); W1T coalesced, ld2 b128 broadcast
  {
    const float* W1T = params + P_W1T;         // [j][256]
    float a0, a1, a2, a3;
    a0 = a1 = a2 = a3 = params[P_B1 + threadIdx.x];
    #pragma unroll 8
    for (int j = 0; j < 64; ++j) {
      float w = W1T[j*256 + threadIdx.x];      // 1 KB contiguous per block-instr
      float4 xj = *(const float4*)(ld2 + j*4); // broadcast b128
      a0 += w*xj.x; a1 += w*xj.y; a2 += w*xj.z; a3 += w*xj.w;
    }
    float av[4] = {a0, a1, a2, a3};
    #pragma unroll
    for (int t2 = 0; t2 < 4; ++t2) {
      float v = av[t2];
      float u = 1.5957691f*v + 0.07135481f*v*v*v;   // tanh-GELU sigmoid form
      hbuf[t2*256 + threadIdx.x] = v * rcpf(1.f + __expf(-u));
    }
  }
  __syncthreads();
  // phase 2: y = hidden @ W2^T + b2; W2T coalesced, hbuf broadcast
  int j = lane;
  int t = t0 + tt, b = t >> 10;
  float y = params[P_B2 + j];
  const float* W2T = params + P_W2T;           // [k][64]
  const float* hb = hbuf + tt*256;
  #pragma unroll 8
  for (int k = 0; k < 256; ++k) y += W2T[k*64 + j] * hb[k];
  float z = ld2[j*4 + tt] + y;
  float s = z, s2 = z*z;
  #pragma unroll
  for (int off = 32; off; off >>= 1) { s += __shfl_xor(s, off); s2 += __shfl_xor(s2, off); }
  float mu  = s  * (1.f/64.f);
  float var = s2 * (1.f/64.f) - mu*mu;
  float y2 = (z - mu) * rsqrtf(var + 1e-5f) * params[P_G2 + j] + params[P_BE2 + j];
  bool is64 = ((tok32[1] | tok32[3] | tok32[5] | tok32[7]) == 0);
  int tok = is64 ? tok32[t*2] : tok32[t];
  int i = j >> 2, e = j & 3;
  float sv = ldf<ISBF>(sens_emb, tok*16 + i) + recv * params[P_SAL + i];
  float sg = rcpf(1.f + __expf(-sv));
  float blk = blocks[t*64 + j];
  float nb = blk + (y2 - blk) * sg;
  int rb = i >> 2, cb = i & 3, r = e >> 1, c = e & 1;
  int oidx = t*64 + (rb*2 + r)*8 + cb*2 + c;
  if (ISBF) ((__hip_bfloat16*)out)[oidx] = __float2bfloat16(nb);
  else      ((float*)out)[oidx] = nb;
}

extern "C" void kernel_launch(void* const* d_in, const int* in_sizes, int n_in,
                              void* d_out, int out_size, void* d_ws, size_t ws_size,
                              hipStream_t stream) {
  const void* M        = d_in[0];
  const int*  tok      = (const int*)d_in[1];
  const void* Wqkv_blk = d_in[2];
  const void* bqkv_blk = d_in[3];
  const void* Wo_blk   = d_in[4];
  const void* bo_blk   = d_in[5];
  const void* Wqkv_c   = d_in[6];
  const void* bqkv_c   = d_in[7];
  const void* Wo_c     = d_in[8];
  const void* bo_c     = d_in[9];
  const void* W1       = d_in[10];
  const void* b1       = d_in[11];
  const void* W2       = d_in[12];
  const void* b2       = d_in[13];
  const void* g1       = d_in[14];
  const void* be1      = d_in[15];
  const void* g2i      = d_in[16];
  const void* be2      = d_in[17];
  const void* sens_emb = d_in[18];
  const void* sens_al  = d_in[19];

  float* ws = (float*)d_ws;
  float* blocks    = ws + OFF_BLOCKS;
  float* qkv_blk   = ws + OFF_QKVB;
  float* recv_part = ws + OFF_RECVP;   // aliases qkv_blk (dead after k_blk_part)
  float* all_blk   = ws + OFF_ALLB;
  float* qkv_c     = ws + OFF_QKVC;
  float* l_c       = ws + OFF_LC;
  float* acc_c     = ws + OFF_ACCC;
  float* ln1       = ws + OFF_LN1;
  float* params    = ws + OFF_PARAMS;

  k_repack<true ><<<64, 256, 0, stream>>>(M, W1, W2, Wqkv_c, Wo_c, Wo_blk, bo_blk,
                                          bqkv_c, bo_c, g1, be1, b1, b2, g2i, be2,
                                          sens_al, params);
  k_repack<false><<<64, 256, 0, stream>>>(M, W1, W2, Wqkv_c, Wo_c, Wo_blk, bo_blk,
                                          bqkv_c, bo_c, g1, be1, b1, b2, g2i, be2,
                                          sens_al, params);
  k_prep<true ><<<256, 256, 0, stream>>>(M, Wqkv_blk, bqkv_blk, blocks, qkv_blk);
  k_prep<false><<<256, 256, 0, stream>>>(M, Wqkv_blk, bqkv_blk, blocks, qkv_blk);
  k_blk_part<<<512, 512, 0, stream>>>(qkv_blk, params, all_blk);
  k_qkv_c<<<1024, 256, 0, stream>>>(all_blk, params, qkv_c);
  k_cross4<<<512, 512, 0, stream>>>(qkv_c, l_c, acc_c);
  k_fin_recv<<<1536, 256, 0, stream>>>(all_blk, acc_c, params, qkv_c, l_c, ln1, recv_part);
  k_ffn_out<true ><<<1024, 256, 0, stream>>>(M, ln1, params, blocks, tok, recv_part,
                                             sens_emb, (void*)d_out);
  k_ffn_out<false><<<1024, 256, 0, stream>>>(M, ln1, params, blocks, tok, recv_part,
                                             sens_emb, (void*)d_out);
}

// Round 12
// 218.527 us; speedup vs baseline: 1.2700x; 1.0202x over previous
//
#include <hip/hip_runtime.h>
#include <hip/hip_bf16.h>
#include <math.h>

// Problem constants (setup_inputs: B=4, T=1024)
#define BB 4
#define TT 1024
#define BT 4096

// Workspace layout (fp32 offsets in floats)
#define OFF_BLOCKS 0          // [BT][64]  blocks in [i*4+e] channel order
#define OFF_QKVB   262144     // [16][BT][12] per-block qkv (dead after k_blk_part)
#define OFF_RECVP  262144     // [B][1024 k][128 src] recv partials (aliases QKVB, 2 MB)
#define OFF_ALLB   1048576    // [BT][64]  per-block MHA output (all_blocks)
#define OFF_QKVC   1310720    // [BT][192] cross qkv
#define OFF_LC     2097152    // [B*8][T]  cross softmax denominators
#define OFF_ACCC   2129920    // [B*8][T][8] cross PV (normalized by l)
#define OFF_LN1    2396160    // [BT][64]  post-LN1 activations
#define OFF_PARAMS 2658304    // repacked fp32 weights (see P_* below)
#define WS_FLOATS  2708624

// Param sub-offsets (floats, relative to OFF_PARAMS)
#define P_W1T    0        // [64 j][256 h]
#define P_W2T    16384    // [256 k][64 j]
#define P_WQCT   32768    // [64 j][192 c]
#define P_WOCT   45056    // [64 m][64 j]
#define P_WOBLK  49152    // [16 i][4 j][4 m]
#define P_BOBLK  49408
#define P_BQC    49472
#define P_BOC    49664
#define P_G1     49728
#define P_BE1    49792
#define P_B1     49856
#define P_B2     50112
#define P_G2     50176
#define P_BE2    50240
#define P_SAL    50304
#define P_TOTAL  50320

__device__ inline float rcpf(float x) { return __builtin_amdgcn_rcpf(x); }

// ---------- in-block dtype detection (wave-uniform) ----------
__device__ inline bool detect_bf16(const void* M) {
  const unsigned short* h = (const unsigned short*)M;
  unsigned short v = h[threadIdx.x & 63];
  int e = (v >> 7) & 0xff;
  unsigned long long m = __ballot((e >= 90) && (e <= 141));
  return __popcll(m) >= 58;
}

template <bool ISBF>
__device__ inline float ldf(const void* p, int i) {
  if (ISBF) return __bfloat162float(((const __hip_bfloat16*)p)[i]);
  else      return ((const float*)p)[i];
}

// ---------- K1: fused blocks-gather/per-block-QKV (blocks 0..255) + weight repack (256..271) ----------
template <bool ISBF>
__global__ void __launch_bounds__(256) k_prep2(
    const void* __restrict__ M,
    const void* __restrict__ Wqkv_blk,
    const void* __restrict__ bqkv_blk,
    const void* __restrict__ W1, const void* __restrict__ W2,
    const void* __restrict__ Wqkv_c, const void* __restrict__ Wo_c,
    const void* __restrict__ Wo_blk, const void* __restrict__ bo_blk,
    const void* __restrict__ bqkv_c, const void* __restrict__ bo_c,
    const void* __restrict__ g1, const void* __restrict__ be1,
    const void* __restrict__ b1, const void* __restrict__ b2,
    const void* __restrict__ g2, const void* __restrict__ be2,
    const void* __restrict__ sens_al,
    float* __restrict__ blocks, float* __restrict__ qkv_blk,
    float* __restrict__ params) {
  if (detect_bf16(M) != ISBF) return;
  if (blockIdx.x < 256) {
    int g = blockIdx.x * 256 + threadIdx.x;      // 65536 = 16 blocks * 4096 tokens
    int i = g >> 12, bt = g & 4095;
    int rb = i >> 2, cb = i & 3;
    float x[4];
    #pragma unroll
    for (int r = 0; r < 2; ++r)
      #pragma unroll
      for (int c = 0; c < 2; ++c)
        x[r*2+c] = ldf<ISBF>(M, bt*64 + (rb*2+r)*8 + cb*2 + c);
    float* bo = blocks + bt*64 + i*4;
    #pragma unroll
    for (int j = 0; j < 4; ++j) bo[j] = x[j];
    float* o = qkv_blk + (i*BT + bt) * 12;
    #pragma unroll
    for (int c = 0; c < 12; ++c) {
      float a = ldf<ISBF>(bqkv_blk, i*12 + c);
      #pragma unroll
      for (int j = 0; j < 4; ++j) a += ldf<ISBF>(Wqkv_blk, i*48 + c*4 + j) * x[j];
      o[c] = a;
    }
  } else {
    for (int o = (blockIdx.x - 256)*256 + threadIdx.x; o < P_TOTAL; o += 16*256) {
      float v;
      if      (o < 16384) { int j = o >> 8, h2 = o & 255; v = ldf<ISBF>(W1, h2*64 + j); }
      else if (o < 32768) { int q = o - 16384; int k = q >> 6, j = q & 63; v = ldf<ISBF>(W2, j*256 + k); }
      else if (o < 45056) { int q = o - 32768; int j = q / 192, c = q % 192; v = ldf<ISBF>(Wqkv_c, c*64 + j); }
      else if (o < 49152) { int q = o - 45056; int m = q >> 6, j = q & 63; v = ldf<ISBF>(Wo_c, j*64 + m); }
      else if (o < 49408) v = ldf<ISBF>(Wo_blk, o - 49152);
      else if (o < 49472) v = ldf<ISBF>(bo_blk, o - 49408);
      else if (o < 49664) v = ldf<ISBF>(bqkv_c, o - 49472);
      else if (o < 49728) v = ldf<ISBF>(bo_c,   o - 49664);
      else if (o < 49792) v = ldf<ISBF>(g1,     o - 49728);
      else if (o < 49856) v = ldf<ISBF>(be1,    o - 49792);
      else if (o < 50112) v = ldf<ISBF>(b1,     o - 49856);
      else if (o < 50176) v = ldf<ISBF>(b2,     o - 50112);
      else if (o < 50240) v = ldf<ISBF>(g2,     o - 50176);
      else if (o < 50304) v = ldf<ISBF>(be2,    o - 50240);
      else                v = ldf<ISBF>(sens_al, o - 50304);
      params[o] = v;
    }
  }
}

// ---------- K2: per-block attention, LDS-staged K/V, 8-wave key-split, 2 q/thread ----------
__global__ void __launch_bounds__(512) k_blk_part(
    const float* __restrict__ qkv_blk,
    const float* __restrict__ params,
    float* __restrict__ all_blocks) {
  __shared__ float4 kv4[3072];       // 48 KB: the (i,b) slab [1024 rows][12 floats]
  __shared__ float red[128*49];      // stride 49 (odd -> conflict-free)
  float* kv = (float*)kv4;
  int bid = blockIdx.x;              // grid 512 = 16i * 4b * 8qt
  int qt = bid & 7, b = (bid >> 3) & 3, i = bid >> 5;
  int tid = threadIdx.x;
  int wv = __builtin_amdgcn_readfirstlane(tid) >> 6;
  int ql = tid & 63;
  const float4* slab = (const float4*)(qkv_blk + (size_t)(i*BT + b*TT) * 12);
  #pragma unroll
  for (int s = 0; s < 6; ++s) kv4[tid + s*512] = slab[tid + s*512];
  __syncthreads();
  int qa = qt*128 + ql, qb = qa + 64;
  const float* qra = kv + qa*12;
  const float* qrb = kv + qb*12;
  const float S2 = 0.70710678f;      // 1/sqrt(Dh=2)
  float qa00 = qra[0]*S2, qa01 = qra[1]*S2, qa10 = qra[2]*S2, qa11 = qra[3]*S2;
  float qb00 = qrb[0]*S2, qb01 = qrb[1]*S2, qb10 = qrb[2]*S2, qb11 = qrb[3]*S2;
  float la0=0.f, la1=0.f, aa00=0.f, aa01=0.f, aa10=0.f, aa11=0.f;
  float lb0=0.f, lb1=0.f, ab00=0.f, ab01=0.f, ab10=0.f, ab11=0.f;
  int kbeg = wv*128;
  #pragma unroll 4
  for (int k = kbeg; k < kbeg + 128; ++k) {
    const float* kr = kv + k*12 + 4;      // LDS broadcast
    float k0=kr[0], k1=kr[1], k2=kr[2], k3=kr[3];
    float v0=kr[4], v1=kr[5], v2=kr[6], v3=kr[7];
    float pa0 = __expf(qa00*k0 + qa01*k1);
    float pa1 = __expf(qa10*k2 + qa11*k3);
    float pb0 = __expf(qb00*k0 + qb01*k1);
    float pb1 = __expf(qb10*k2 + qb11*k3);
    la0 += pa0; aa00 += pa0*v0; aa01 += pa0*v1;
    la1 += pa1; aa10 += pa1*v2; aa11 += pa1*v3;
    lb0 += pb0; ab00 += pb0*v0; ab01 += pb0*v1;
    lb1 += pb1; ab10 += pb1*v2; ab11 += pb1*v3;
  }
  float* ra = red + ql*49 + wv*6;
  ra[0]=la0; ra[1]=la1; ra[2]=aa00; ra[3]=aa01; ra[4]=aa10; ra[5]=aa11;
  float* rb = red + (ql+64)*49 + wv*6;
  rb[0]=lb0; rb[1]=lb1; rb[2]=ab00; rb[3]=ab01; rb[4]=ab10; rb[5]=ab11;
  __syncthreads();
  if (tid < 128) {
    float s[6] = {0.f,0.f,0.f,0.f,0.f,0.f};
    #pragma unroll
    for (int w = 0; w < 8; ++w) {
      const float* p = red + tid*49 + w*6;
      #pragma unroll
      for (int c = 0; c < 6; ++c) s[c] += p[c];
    }
    float r0 = rcpf(s[0]), r1 = rcpf(s[1]);
    float o[4] = { s[2]*r0, s[3]*r0, s[4]*r1, s[5]*r1 };
    int q2 = qt*128 + tid;
    const float* pWo = params + P_WOBLK + i*16;
    float* outp = all_blocks + (size_t)(b*TT + q2)*64 + i*4;
    #pragma unroll
    for (int j = 0; j < 4; ++j) {
      float a = params[P_BOBLK + i*4 + j];
      #pragma unroll
      for (int m2 = 0; m2 < 4; ++m2) a += pWo[j*4 + m2] * o[m2];
      outp[j] = a;
    }
  }
}

// ---------- K3: cross QKV projection, coalesced transposed weights ----------
__global__ void __launch_bounds__(256) k_qkv_c(
    const float* __restrict__ all_blocks,
    const float* __restrict__ params,
    float* __restrict__ qkv_c) {
  __shared__ float xs[4*64];
  int t0 = blockIdx.x * 4;           // grid 1024, wave per token
  xs[threadIdx.x] = all_blocks[t0*64 + threadIdx.x];
  __syncthreads();
  int tt = threadIdx.x >> 6, lane = threadIdx.x & 63;
  int t = t0 + tt;
  const float* x = xs + tt*64;
  const float* WT = params + P_WQCT;           // [j][192]
  float a0 = params[P_BQC + lane];
  float a1 = params[P_BQC + 64 + lane];
  float a2 = params[P_BQC + 128 + lane];
  #pragma unroll 8
  for (int j = 0; j < 64; ++j) {
    const float* r = WT + j*192;
    float xj = x[j];                           // LDS broadcast
    a0 += r[lane]       * xj;                  // coalesced 256 B
    a1 += r[64 + lane]  * xj;
    a2 += r[128 + lane] * xj;
  }
  float* o = qkv_c + (size_t)t*192;
  o[lane] = a0; o[64 + lane] = a1; o[128 + lane] = a2;
}

// ---------- K4: cross attention, LDS-staged K/V slab, 8-wave key-split ----------
__global__ void __launch_bounds__(512) k_cross5(
    const float* __restrict__ qkv_c,
    float* __restrict__ l_c, float* __restrict__ acc_c) {
  __shared__ float kv[1024*16];      // 64 KB; reused as reduction scratch after loop
  int bid = blockIdx.x;              // grid 512 = 4b * 8h * 16qt
  int qt = bid & 15, h = (bid >> 4) & 7, b = bid >> 7;
  int tid = threadIdx.x;
  int wv = __builtin_amdgcn_readfirstlane(tid) >> 6;
  int ql = tid & 63;
  int h8 = h*8;
  const float* base = qkv_c + (size_t)b*TT*192;
  // stage the (b,h) K/V slab: 1024 rows x (K8|V8), coalesced float4
  #pragma unroll
  for (int r = tid; r < 1024; r += 512) {
    const float4* kp = (const float4*)(base + (size_t)r*192 + 64 + h8);
    const float4* vp = (const float4*)(base + (size_t)r*192 + 128 + h8);
    float4 k0 = kp[0], k1 = kp[1], v0 = vp[0], v1 = vp[1];
    float4* dst = (float4*)(kv + r*16);
    dst[0] = k0; dst[1] = k1; dst[2] = v0; dst[3] = v1;
  }
  int q = qt*64 + ql;
  float qv[8];
  #pragma unroll
  for (int c = 0; c < 8; ++c) qv[c] = base[(size_t)q*192 + h8 + c] * 0.35355339f; // 1/sqrt(8)
  __syncthreads();
  float l = 0.f, acc[8];
  #pragma unroll
  for (int c = 0; c < 8; ++c) acc[c] = 0.f;
  int kbeg = wv*128;
  #pragma unroll 4
  for (int k = kbeg; k < kbeg + 128; ++k) {
    const float* kr = kv + k*16;     // uniform address -> LDS broadcast
    float s = qv[0]*kr[0] + qv[1]*kr[1] + qv[2]*kr[2] + qv[3]*kr[3]
            + qv[4]*kr[4] + qv[5]*kr[5] + qv[6]*kr[6] + qv[7]*kr[7];
    float p = __expf(s);
    l += p;
    #pragma unroll
    for (int c = 0; c < 8; ++c) acc[c] += p * kr[8 + c];
  }
  __syncthreads();                   // all kv reads done; reuse as reduction scratch
  float* red = kv;                   // [ql][wv*9+c], stride 73 (odd -> conflict-free)
  float* rr = red + ql*73 + wv*9;
  rr[0] = l;
  #pragma unroll
  for (int c = 0; c < 8; ++c) rr[1+c] = acc[c];
  __syncthreads();
  if (tid < 64) {
    float ls = 0.f, as[8];
    #pragma unroll
    for (int c = 0; c < 8; ++c) as[c] = 0.f;
    #pragma unroll
    for (int w = 0; w < 8; ++w) {
      const float* p = red + tid*73 + w*9;
      ls += p[0];
      #pragma unroll
      for (int c = 0; c < 8; ++c) as[c] += p[1+c];
    }
    float invl = rcpf(ls);
    int q2 = qt*64 + tid;
    int idx = (b*8 + h)*TT + q2;
    l_c[idx] = ls;
    #pragma unroll
    for (int c = 0; c < 8; ++c) acc_c[idx*8 + c] = as[c] * invl;   // normalized PV
  }
}

// ---------- K5: fused finalize-cross (blocks 0..1023) + recv partials (1024..1535) ----------
__global__ void __launch_bounds__(256) k_fin_recv(
    const float* __restrict__ all_blocks,
    const float* __restrict__ acc_c,
    const float* __restrict__ params,
    const float* __restrict__ qkv_c,
    const float* __restrict__ l_c,
    float* __restrict__ ln1,
    float* __restrict__ recv_part) {
  __shared__ float pvs[4*64];
  __shared__ float qbuf[256*9];      // staged q-rows + invl (recv branch)
  int tt = threadIdx.x >> 6, lane = threadIdx.x & 63;
  if (blockIdx.x < 1024) {
    // finalize: Wo_c^T coalesced projection, residual, LN1
    int j = lane;
    int t = blockIdx.x*4 + tt;
    int b = t >> 10, tl = t & 1023;
    int h = j >> 3;
    int idx = (b*8 + h)*TT + tl;
    pvs[tt*64 + j] = acc_c[idx*8 + (j & 7)];
    __syncthreads();
    float a = params[P_BOC + j];
    const float* WoT = params + P_WOCT;        // [m][64]
    const float* p = pvs + tt*64;
    #pragma unroll 8
    for (int m = 0; m < 64; ++m) a += WoT[m*64 + j] * p[m];   // coalesced + broadcast
    float x = all_blocks[t*64 + j] + a;
    float s = x, s2 = x*x;
    #pragma unroll
    for (int off = 32; off; off >>= 1) { s += __shfl_xor(s, off); s2 += __shfl_xor(s2, off); }
    float mu  = s  * (1.f/64.f);
    float var = s2 * (1.f/64.f) - mu*mu;
    float y = (x - mu) * rsqrtf(var + 1e-5f) * params[P_G1 + j] + params[P_BE1 + j];
    ln1[t*64 + j] = y;
  } else {
    // recv: 4 waves share (b,h,kt); stage 256 q-rows + invl in LDS, loop from LDS
    int obase = (blockIdx.x - 1024)*4;         // aligned: qs0 in {0,4,8,12}
    int qs0 = obase & 15, kt = (obase >> 4) & 3, h = (obase >> 6) & 7, b = obase >> 9;
    int h8 = h*8;
    const float* base = qkv_c + (size_t)b*TT*192;
    const float* lrow = l_c + (b*8 + h)*TT;
    int qbase = qs0*64;
    {
      int r = threadIdx.x;                     // 256 rows
      const float4* qp = (const float4*)(base + (size_t)(qbase + r)*192 + h8);
      float4 a = qp[0], bq = qp[1];
      float* dst = qbuf + r*9;
      dst[0]=a.x; dst[1]=a.y; dst[2]=a.z; dst[3]=a.w;
      dst[4]=bq.x; dst[5]=bq.y; dst[6]=bq.z; dst[7]=bq.w;
      dst[8] = rcpf(lrow[qbase + r]);
    }
    // register K tile: thread owns 4 keys
    float kv[4][8];
    #pragma unroll
    for (int i = 0; i < 4; ++i) {
      int k = kt*256 + i*64 + lane;
      #pragma unroll
      for (int c = 0; c < 8; ++c)
        kv[i][c] = base[(size_t)k*192 + 64 + h8 + c] * 0.35355339f;
    }
    __syncthreads();
    float acc[4] = {0.f, 0.f, 0.f, 0.f};
    #pragma unroll 4
    for (int qq = 0; qq < 64; ++qq) {
      const float* qr = qbuf + (tt*64 + qq)*9; // uniform -> LDS broadcast
      float q0=qr[0],q1=qr[1],q2=qr[2],q3=qr[3],q4=qr[4],q5=qr[5],q6=qr[6],q7=qr[7];
      float invl = qr[8];
      #pragma unroll
      for (int i = 0; i < 4; ++i) {
        float s = q0*kv[i][0] + q1*kv[i][1] + q2*kv[i][2] + q3*kv[i][3]
                + q4*kv[i][4] + q5*kv[i][5] + q6*kv[i][6] + q7*kv[i][7];
        acc[i] += __expf(s) * invl;
      }
    }
    // layout [b][k][src]: reducer reads contiguous; 4 scattered stores/thread
    int src = h*16 + qs0 + tt;
    #pragma unroll
    for (int i = 0; i < 4; ++i) {
      int k = kt*256 + i*64 + lane;
      recv_part[((size_t)(b*1024 + k))*128 + src] = acc[i];
    }
  }
}

// ---------- K6: FFN + LN2 + fused recv-reduce + gate + un-blocking ----------
template <bool ISBF>
__global__ void __launch_bounds__(256) k_ffn_out(
    const void* __restrict__ M,
    const float* __restrict__ ln1,
    const float* __restrict__ params,
    const float* __restrict__ blocks,
    const int* __restrict__ tok32,
    const float* __restrict__ recv_part,
    const void* __restrict__ sens_emb,
    void* __restrict__ out) {
  if (detect_bf16(M) != ISBF) return;
  __shared__ float ld2[256];     // [j][tt]
  __shared__ float hbuf[1024];   // [tt][k]
  int t0 = blockIdx.x * 4;       // grid 1024, wave per token
  int tt = threadIdx.x >> 6, lane = threadIdx.x & 63;
  ld2[lane*4 + tt] = ln1[(t0 + tt)*64 + lane];
  // recv reduce: contiguous 512 B per token
  float recv;
  {
    int t = t0 + tt, b = t >> 10, k = t & 1023;
    const float* rp = recv_part + ((size_t)(b*1024 + k))*128;
    float s = rp[lane] + rp[lane + 64];
    #pragma unroll
    for (int off = 32; off; off >>= 1) s += __shfl_xor(s, off);
    recv = s * (1.f/8192.f);     // /(H=8 * T=1024)
  }
  __syncthreads();
  // phase 1: hidden = gelu(ln1 @ W1^T + b1); W1T coalesced, ld2 b128 broadcast
  {
    const float* W1T = params + P_W1T;         // [j][256]
    float a0, a1, a2, a3;
    a0 = a1 = a2 = a3 = params[P_B1 + threadIdx.x];
    #pragma unroll 8
    for (int j = 0; j < 64; ++j) {
      float w = W1T[j*256 + threadIdx.x];      // 1 KB contiguous per block-instr
      float4 xj = *(const float4*)(ld2 + j*4); // broadcast b128
      a0 += w*xj.x; a1 += w*xj.y; a2 += w*xj.z; a3 += w*xj.w;
    }
    float av[4] = {a0, a1, a2, a3};
    #pragma unroll
    for (int t2 = 0; t2 < 4; ++t2) {
      float v = av[t2];
      float u = 1.5957691f*v + 0.07135481f*v*v*v;   // tanh-GELU sigmoid form
      hbuf[t2*256 + threadIdx.x] = v * rcpf(1.f + __expf(-u));
    }
  }
  __syncthreads();
  // phase 2: y = hidden @ W2^T + b2; W2T coalesced, hbuf broadcast
  int j = lane;
  int t = t0 + tt, b = t >> 10;
  float y = params[P_B2 + j];
  const float* W2T = params + P_W2T;           // [k][64]
  const float* hb = hbuf + tt*256;
  #pragma unroll 8
  for (int k = 0; k < 256; ++k) y += W2T[k*64 + j] * hb[k];
  float z = ld2[j*4 + tt] + y;
  float s = z, s2 = z*z;
  #pragma unroll
  for (int off = 32; off; off >>= 1) { s += __shfl_xor(s, off); s2 += __shfl_xor(s2, off); }
  float mu  = s  * (1.f/64.f);
  float var = s2 * (1.f/64.f) - mu*mu;
  float y2 = (z - mu) * rsqrtf(var + 1e-5f) * params[P_G2 + j] + params[P_BE2 + j];
  bool is64 = ((tok32[1] | tok32[3] | tok32[5] | tok32[7]) == 0);
  int tok = is64 ? tok32[t*2] : tok32[t];
  int i = j >> 2, e = j & 3;
  float sv = ldf<ISBF>(sens_emb, tok*16 + i) + recv * params[P_SAL + i];
  float sg = rcpf(1.f + __expf(-sv));
  float blk = blocks[t*64 + j];
  float nb = blk + (y2 - blk) * sg;
  int rb = i >> 2, cb = i & 3, r = e >> 1, c = e & 1;
  int oidx = t*64 + (rb*2 + r)*8 + cb*2 + c;
  if (ISBF) ((__hip_bfloat16*)out)[oidx] = __float2bfloat16(nb);
  else      ((float*)out)[oidx] = nb;
}

extern "C" void kernel_launch(void* const* d_in, const int* in_sizes, int n_in,
                              void* d_out, int out_size, void* d_ws, size_t ws_size,
                              hipStream_t stream) {
  const void* M        = d_in[0];
  const int*  tok      = (const int*)d_in[1];
  const void* Wqkv_blk = d_in[2];
  const void* bqkv_blk = d_in[3];
  const void* Wo_blk   = d_in[4];
  const void* bo_blk   = d_in[5];
  const void* Wqkv_c   = d_in[6];
  const void* bqkv_c   = d_in[7];
  const void* Wo_c     = d_in[8];
  const void* bo_c     = d_in[9];
  const void* W1       = d_in[10];
  const void* b1       = d_in[11];
  const void* W2       = d_in[12];
  const void* b2       = d_in[13];
  const void* g1       = d_in[14];
  const void* be1      = d_in[15];
  const void* g2i      = d_in[16];
  const void* be2      = d_in[17];
  const void* sens_emb = d_in[18];
  const void* sens_al  = d_in[19];

  float* ws = (float*)d_ws;
  float* blocks    = ws + OFF_BLOCKS;
  float* qkv_blk   = ws + OFF_QKVB;
  float* recv_part = ws + OFF_RECVP;   // aliases qkv_blk (dead after k_blk_part)
  float* all_blk   = ws + OFF_ALLB;
  float* qkv_c     = ws + OFF_QKVC;
  float* l_c       = ws + OFF_LC;
  float* acc_c     = ws + OFF_ACCC;
  float* ln1       = ws + OFF_LN1;
  float* params    = ws + OFF_PARAMS;

  k_prep2<true ><<<272, 256, 0, stream>>>(M, Wqkv_blk, bqkv_blk, W1, W2, Wqkv_c, Wo_c,
                                          Wo_blk, bo_blk, bqkv_c, bo_c, g1, be1, b1, b2,
                                          g2i, be2, sens_al, blocks, qkv_blk, params);
  k_prep2<false><<<272, 256, 0, stream>>>(M, Wqkv_blk, bqkv_blk, W1, W2, Wqkv_c, Wo_c,
                                          Wo_blk, bo_blk, bqkv_c, bo_c, g1, be1, b1, b2,
                                          g2i, be2, sens_al, blocks, qkv_blk, params);
  k_blk_part<<<512, 512, 0, stream>>>(qkv_blk, params, all_blk);
  k_qkv_c<<<1024, 256, 0, stream>>>(all_blk, params, qkv_c);
  k_cross5<<<512, 512, 0, stream>>>(qkv_c, l_c, acc_c);
  k_fin_recv<<<1536, 256, 0, stream>>>(all_blk, acc_c, params, qkv_c, l_c, ln1, recv_part);
  k_ffn_out<true ><<<1024, 256, 0, stream>>>(M, ln1, params, blocks, tok, recv_part,
                                             sens_emb, (void*)d_out);
  k_ffn_out<false><<<1024, 256, 0, stream>>>(M, ln1, params, blocks, tok, recv_part,
                                             sens_emb, (void*)d_out);
}

// Round 13
// 213.377 us; speedup vs baseline: 1.3006x; 1.0241x over previous
//
#include <hip/hip_runtime.h>
#include <hip/hip_bf16.h>
#include <math.h>

// Problem constants (setup_inputs: B=4, T=1024)
#define BB 4
#define TT 1024
#define BT 4096

// Workspace layout (fp32 offsets in floats)
#define OFF_BLOCKS 0          // [BT][64]  blocks in [i*4+e] channel order
#define OFF_QKVB   262144     // [16][BT][12] per-block qkv (dead after k_blk_part)
#define OFF_RECVP  262144     // [B][1024 k][128 src] recv partials (aliases QKVB, 2 MB)
#define OFF_ALLB   1048576    // [BT][64]  per-block MHA output (all_blocks)
#define OFF_QKVC   1310720    // [BT][192] cross qkv
#define OFF_LC     2097152    // [B*8][T]  cross softmax denominators
#define OFF_ACCC   2129920    // [B*8][T][8] cross PV (normalized by l)
#define OFF_LN1    2396160    // [BT][64]  post-LN1 activations
#define OFF_PARAMS 2658304    // repacked fp32 weights (see P_* below)
#define WS_FLOATS  2708624

// Param sub-offsets (floats, relative to OFF_PARAMS)
#define P_W1T    0        // [64 j][256 h]
#define P_W2T    16384    // [256 k][64 j]
#define P_WQCT   32768    // [64 j][192 c]
#define P_WOCT   45056    // [64 m][64 j]
#define P_WOBLK  49152    // [16 i][4 j][4 m]
#define P_BOBLK  49408
#define P_BQC    49472
#define P_BOC    49664
#define P_G1     49728
#define P_BE1    49792
#define P_B1     49856
#define P_B2     50112
#define P_G2     50176
#define P_BE2    50240
#define P_SAL    50304
#define P_TOTAL  50320

__device__ inline float rcpf(float x) { return __builtin_amdgcn_rcpf(x); }

// ---------- in-block dtype detection (wave-uniform) ----------
__device__ inline bool detect_bf16(const void* M) {
  const unsigned short* h = (const unsigned short*)M;
  unsigned short v = h[threadIdx.x & 63];
  int e = (v >> 7) & 0xff;
  unsigned long long m = __ballot((e >= 90) && (e <= 141));
  return __popcll(m) >= 58;
}

template <bool ISBF>
__device__ inline float ldf(const void* p, int i) {
  if (ISBF) return __bfloat162float(((const __hip_bfloat16*)p)[i]);
  else      return ((const float*)p)[i];
}

// ---------- K1: fused blocks-gather/per-block-QKV (blocks 0..255) + weight repack ----------
template <bool ISBF>
__global__ void __launch_bounds__(256) k_prep2(
    const void* __restrict__ M,
    const void* __restrict__ Wqkv_blk,
    const void* __restrict__ bqkv_blk,
    const void* __restrict__ W1, const void* __restrict__ W2,
    const void* __restrict__ Wqkv_c, const void* __restrict__ Wo_c,
    const void* __restrict__ Wo_blk, const void* __restrict__ bo_blk,
    const void* __restrict__ bqkv_c, const void* __restrict__ bo_c,
    const void* __restrict__ g1, const void* __restrict__ be1,
    const void* __restrict__ b1, const void* __restrict__ b2,
    const void* __restrict__ g2, const void* __restrict__ be2,
    const void* __restrict__ sens_al,
    float* __restrict__ blocks, float* __restrict__ qkv_blk,
    float* __restrict__ params) {
  if (detect_bf16(M) != ISBF) return;
  if (blockIdx.x < 256) {
    int g = blockIdx.x * 256 + threadIdx.x;      // 65536 = 16 blocks * 4096 tokens
    int i = g >> 12, bt = g & 4095;
    int rb = i >> 2, cb = i & 3;
    float x[4];
    #pragma unroll
    for (int r = 0; r < 2; ++r)
      #pragma unroll
      for (int c = 0; c < 2; ++c)
        x[r*2+c] = ldf<ISBF>(M, bt*64 + (rb*2+r)*8 + cb*2 + c);
    float* bo = blocks + bt*64 + i*4;
    #pragma unroll
    for (int j = 0; j < 4; ++j) bo[j] = x[j];
    float* o = qkv_blk + (i*BT + bt) * 12;
    #pragma unroll
    for (int c = 0; c < 12; ++c) {
      float a = ldf<ISBF>(bqkv_blk, i*12 + c);
      #pragma unroll
      for (int j = 0; j < 4; ++j) a += ldf<ISBF>(Wqkv_blk, i*48 + c*4 + j) * x[j];
      o[c] = a;
    }
  } else {
    for (int o = (blockIdx.x - 256)*256 + threadIdx.x; o < P_TOTAL; o += 16*256) {
      float v;
      if      (o < 16384) { int j = o >> 8, h2 = o & 255; v = ldf<ISBF>(W1, h2*64 + j); }
      else if (o < 32768) { int q = o - 16384; int k = q >> 6, j = q & 63; v = ldf<ISBF>(W2, j*256 + k); }
      else if (o < 45056) { int q = o - 32768; int j = q / 192, c = q % 192; v = ldf<ISBF>(Wqkv_c, c*64 + j); }
      else if (o < 49152) { int q = o - 45056; int m = q >> 6, j = q & 63; v = ldf<ISBF>(Wo_c, j*64 + m); }
      else if (o < 49408) v = ldf<ISBF>(Wo_blk, o - 49152);
      else if (o < 49472) v = ldf<ISBF>(bo_blk, o - 49408);
      else if (o < 49664) v = ldf<ISBF>(bqkv_c, o - 49472);
      else if (o < 49728) v = ldf<ISBF>(bo_c,   o - 49664);
      else if (o < 49792) v = ldf<ISBF>(g1,     o - 49728);
      else if (o < 49856) v = ldf<ISBF>(be1,    o - 49792);
      else if (o < 50112) v = ldf<ISBF>(b1,     o - 49856);
      else if (o < 50176) v = ldf<ISBF>(b2,     o - 50112);
      else if (o < 50240) v = ldf<ISBF>(g2,     o - 50176);
      else if (o < 50304) v = ldf<ISBF>(be2,    o - 50240);
      else                v = ldf<ISBF>(sens_al, o - 50304);
      params[o] = v;
    }
  }
}

// ---------- K2: per-block attention, LDS-staged K/V, 8-wave key-split, 2 q/thread ----------
__global__ void __launch_bounds__(512) k_blk_part(
    const float* __restrict__ qkv_blk,
    const float* __restrict__ params,
    float* __restrict__ all_blocks) {
  __shared__ float4 kv4[3072];       // 48 KB: the (i,b) slab [1024 rows][12 floats]
  __shared__ float red[128*49];      // stride 49 (odd -> conflict-free)
  float* kv = (float*)kv4;
  int bid = blockIdx.x;              // grid 512 = 16i * 4b * 8qt
  int qt = bid & 7, b = (bid >> 3) & 3, i = bid >> 5;
  int tid = threadIdx.x;
  int wv = __builtin_amdgcn_readfirstlane(tid) >> 6;
  int ql = tid & 63;
  const float4* slab = (const float4*)(qkv_blk + (size_t)(i*BT + b*TT) * 12);
  #pragma unroll
  for (int s = 0; s < 6; ++s) kv4[tid + s*512] = slab[tid + s*512];
  __syncthreads();
  int qa = qt*128 + ql, qb = qa + 64;
  const float* qra = kv + qa*12;
  const float* qrb = kv + qb*12;
  const float S2 = 0.70710678f;      // 1/sqrt(Dh=2)
  float qa00 = qra[0]*S2, qa01 = qra[1]*S2, qa10 = qra[2]*S2, qa11 = qra[3]*S2;
  float qb00 = qrb[0]*S2, qb01 = qrb[1]*S2, qb10 = qrb[2]*S2, qb11 = qrb[3]*S2;
  float la0=0.f, la1=0.f, aa00=0.f, aa01=0.f, aa10=0.f, aa11=0.f;
  float lb0=0.f, lb1=0.f, ab00=0.f, ab01=0.f, ab10=0.f, ab11=0.f;
  int kbeg = wv*128;
  #pragma unroll 4
  for (int k = kbeg; k < kbeg + 128; ++k) {
    const float* kr = kv + k*12 + 4;      // LDS broadcast
    float k0=kr[0], k1=kr[1], k2=kr[2], k3=kr[3];
    float v0=kr[4], v1=kr[5], v2=kr[6], v3=kr[7];
    float pa0 = __expf(qa00*k0 + qa01*k1);
    float pa1 = __expf(qa10*k2 + qa11*k3);
    float pb0 = __expf(qb00*k0 + qb01*k1);
    float pb1 = __expf(qb10*k2 + qb11*k3);
    la0 += pa0; aa00 += pa0*v0; aa01 += pa0*v1;
    la1 += pa1; aa10 += pa1*v2; aa11 += pa1*v3;
    lb0 += pb0; ab00 += pb0*v0; ab01 += pb0*v1;
    lb1 += pb1; ab10 += pb1*v2; ab11 += pb1*v3;
  }
  float* ra = red + ql*49 + wv*6;
  ra[0]=la0; ra[1]=la1; ra[2]=aa00; ra[3]=aa01; ra[4]=aa10; ra[5]=aa11;
  float* rb = red + (ql+64)*49 + wv*6;
  rb[0]=lb0; rb[1]=lb1; rb[2]=ab00; rb[3]=ab01; rb[4]=ab10; rb[5]=ab11;
  __syncthreads();
  if (tid < 128) {
    float s[6] = {0.f,0.f,0.f,0.f,0.f,0.f};
    #pragma unroll
    for (int w = 0; w < 8; ++w) {
      const float* p = red + tid*49 + w*6;
      #pragma unroll
      for (int c = 0; c < 6; ++c) s[c] += p[c];
    }
    float r0 = rcpf(s[0]), r1 = rcpf(s[1]);
    float o[4] = { s[2]*r0, s[3]*r0, s[4]*r1, s[5]*r1 };
    int q2 = qt*128 + tid;
    const float* pWo = params + P_WOBLK + i*16;
    float* outp = all_blocks + (size_t)(b*TT + q2)*64 + i*4;
    #pragma unroll
    for (int j = 0; j < 4; ++j) {
      float a = params[P_BOBLK + i*4 + j];
      #pragma unroll
      for (int m2 = 0; m2 < 4; ++m2) a += pWo[j*4 + m2] * o[m2];
      outp[j] = a;
    }
  }
}

// ---------- K3: cross QKV projection, LDS-staged transposed weights ----------
__global__ void __launch_bounds__(256) k_qkv_c2(
    const float* __restrict__ all_blocks,
    const float* __restrict__ params,
    float* __restrict__ qkv_c) {
  __shared__ float w[12288];         // WqkvcT [64 j][192 c], 48 KB
  __shared__ float xs[256];
  int tid = threadIdx.x;
  int t0 = blockIdx.x * 4;           // grid 1024, wave per token
  {
    const float4* src = (const float4*)(params + P_WQCT);
    float4* dst = (float4*)w;
    #pragma unroll
    for (int i = tid; i < 3072; i += 256) dst[i] = src[i];
  }
  xs[tid] = all_blocks[t0*64 + tid];
  __syncthreads();
  int tt = tid >> 6, lane = tid & 63;
  int t = t0 + tt;
  const float* x = xs + tt*64;
  float a0 = params[P_BQC + lane];
  float a1 = params[P_BQC + 64 + lane];
  float a2 = params[P_BQC + 128 + lane];
  #pragma unroll 8
  for (int j = 0; j < 64; ++j) {
    const float* r = w + j*192;
    float xj = x[j];                           // LDS broadcast
    a0 += r[lane]       * xj;                  // stride-1 LDS, conflict-free
    a1 += r[64 + lane]  * xj;
    a2 += r[128 + lane] * xj;
  }
  float* o = qkv_c + (size_t)t*192;
  o[lane] = a0; o[64 + lane] = a1; o[128 + lane] = a2;
}

// ---------- K4: cross attention + fused recv, LDS K/V slab, 8-wave key-split ----------
__global__ void __launch_bounds__(512) k_cross6(
    const float* __restrict__ qkv_c,
    float* __restrict__ l_c, float* __restrict__ acc_c,
    float* __restrict__ recv_part) {
  __shared__ float kv[16384];        // K at [k*8] (32 KB) | V at [8192+k*8] (32 KB)
  int bid = blockIdx.x;              // grid 512 = 4b * 8h * 16qt
  int qt = bid & 15, h = (bid >> 4) & 7, b = bid >> 7;
  int tid = threadIdx.x;
  int wv = __builtin_amdgcn_readfirstlane(tid) >> 6;
  int ql = tid & 63;
  int h8 = h*8;
  const float* base = qkv_c + (size_t)b*TT*192;
  // stage K and V slabs, coalesced float4
  #pragma unroll
  for (int r = tid; r < 1024; r += 512) {
    const float4* kp = (const float4*)(base + (size_t)r*192 + 64 + h8);
    const float4* vp = (const float4*)(base + (size_t)r*192 + 128 + h8);
    float4 k0 = kp[0], k1 = kp[1], v0 = vp[0], v1 = vp[1];
    float4* kd = (float4*)(kv + r*8);        kd[0] = k0; kd[1] = k1;
    float4* vd = (float4*)(kv + 8192 + r*8); vd[0] = v0; vd[1] = v1;
  }
  int q = qt*64 + ql;
  float qv[8];
  #pragma unroll
  for (int c = 0; c < 8; ++c) qv[c] = base[(size_t)q*192 + h8 + c] * 0.35355339f; // 1/sqrt(8)
  __syncthreads();
  float l = 0.f, acc[8];
  #pragma unroll
  for (int c = 0; c < 8; ++c) acc[c] = 0.f;
  int kbeg = wv*128;
  #pragma unroll 4
  for (int k = kbeg; k < kbeg + 128; ++k) {
    const float* kr = kv + k*8;          // uniform -> LDS broadcast
    const float* vr = kv + 8192 + k*8;
    float s = qv[0]*kr[0] + qv[1]*kr[1] + qv[2]*kr[2] + qv[3]*kr[3]
            + qv[4]*kr[4] + qv[5]*kr[5] + qv[6]*kr[6] + qv[7]*kr[7];
    float p = __expf(s);
    l += p;
    #pragma unroll
    for (int c = 0; c < 8; ++c) acc[c] += p * vr[c];
  }
  __syncthreads();                     // V reads done; reuse V region as scratch
  float* red  = kv + 8192;             // [ql][wv*9+c] stride 73, 4672 floats
  float* qbuf = kv + 8192 + 4736;      // [64 q][8 qv + invl], 576 floats
  {
    float* rr = red + ql*73 + wv*9;
    rr[0] = l;
    #pragma unroll
    for (int c = 0; c < 8; ++c) rr[1+c] = acc[c];
    if (wv == 0) {                     // wave 0's qv regs are queries 0..63 of this block
      #pragma unroll
      for (int c = 0; c < 8; ++c) qbuf[ql*9 + c] = qv[c];
    }
  }
  __syncthreads();
  if (tid < 64) {
    float ls = 0.f, as[8];
    #pragma unroll
    for (int c = 0; c < 8; ++c) as[c] = 0.f;
    #pragma unroll
    for (int w = 0; w < 8; ++w) {
      const float* p = red + tid*73 + w*9;
      ls += p[0];
      #pragma unroll
      for (int c = 0; c < 8; ++c) as[c] += p[1+c];
    }
    float invl = rcpf(ls);
    int q2 = qt*64 + tid;
    int idx = (b*8 + h)*TT + q2;
    l_c[idx] = ls;
    #pragma unroll
    for (int c = 0; c < 8; ++c) acc_c[idx*8 + c] = as[c] * invl;   // normalized PV
    qbuf[tid*9 + 8] = invl;
  }
  __syncthreads();
  // recv pass: lane owns 2 keys (K region intact in LDS), loops the block's 64 queries
  {
    int k1 = (wv << 7) + ql, k2 = k1 + 64;
    float K1[8], K2[8];
    #pragma unroll
    for (int c = 0; c < 8; ++c) { K1[c] = kv[k1*8 + c]; K2[c] = kv[k2*8 + c]; }
    float r1 = 0.f, r2 = 0.f;
    #pragma unroll 4
    for (int qq = 0; qq < 64; ++qq) {
      const float* qr = qbuf + qq*9;   // uniform -> LDS broadcast
      float s1 = qr[0]*K1[0] + qr[1]*K1[1] + qr[2]*K1[2] + qr[3]*K1[3]
               + qr[4]*K1[4] + qr[5]*K1[5] + qr[6]*K1[6] + qr[7]*K1[7];
      float s2 = qr[0]*K2[0] + qr[1]*K2[1] + qr[2]*K2[2] + qr[3]*K2[3]
               + qr[4]*K2[4] + qr[5]*K2[5] + qr[6]*K2[6] + qr[7]*K2[7];
      float invl = qr[8];
      r1 += __expf(s1) * invl;
      r2 += __expf(s2) * invl;
    }
    int src = h*16 + qt;
    recv_part[((size_t)(b*1024 + k1))*128 + src] = r1;
    recv_part[((size_t)(b*1024 + k2))*128 + src] = r2;
  }
}

// ---------- K5: finalize-cross only (Wo_c^T projection, residual, LN1) ----------
__global__ void __launch_bounds__(256) k_fin(
    const float* __restrict__ all_blocks,
    const float* __restrict__ acc_c,
    const float* __restrict__ params,
    float* __restrict__ ln1) {
  __shared__ float pvs[4*64];
  int tt = threadIdx.x >> 6, j = threadIdx.x & 63;
  int t = blockIdx.x*4 + tt;         // grid 1024
  int b = t >> 10, tl = t & 1023;
  int h = j >> 3;
  int idx = (b*8 + h)*TT + tl;
  pvs[tt*64 + j] = acc_c[idx*8 + (j & 7)];
  __syncthreads();
  float a = params[P_BOC + j];
  const float* WoT = params + P_WOCT;          // [m][64]
  const float* p = pvs + tt*64;
  #pragma unroll 8
  for (int m = 0; m < 64; ++m) a += WoT[m*64 + j] * p[m];   // coalesced + broadcast
  float x = all_blocks[t*64 + j] + a;
  float s = x, s2 = x*x;
  #pragma unroll
  for (int off = 32; off; off >>= 1) { s += __shfl_xor(s, off); s2 += __shfl_xor(s2, off); }
  float mu  = s  * (1.f/64.f);
  float var = s2 * (1.f/64.f) - mu*mu;
  float y = (x - mu) * rsqrtf(var + 1e-5f) * params[P_G1 + j] + params[P_BE1 + j];
  ln1[t*64 + j] = y;
}

// ---------- K6: FFN + LN2 + recv-reduce + gate + un-blocking; LDS-staged W1T/W2T ----------
template <bool ISBF>
__global__ void __launch_bounds__(512) k_ffn_out2(
    const void* __restrict__ M,
    const float* __restrict__ ln1,
    const float* __restrict__ params,
    const float* __restrict__ blocks,
    const int* __restrict__ tok32,
    const float* __restrict__ recv_part,
    const void* __restrict__ sens_emb,
    void* __restrict__ out) {
  if (detect_bf16(M) != ISBF) return;
  __shared__ float w[16384];     // W1T, then re-staged as W2T (64 KB)
  __shared__ float ld2[512];     // [j][tok8]
  __shared__ float hbuf[2048];   // [tok8][256]
  int tid = threadIdx.x;
  int t0 = blockIdx.x * 8;       // grid 512, 8 tokens per block
  int wv = tid >> 6, lane = tid & 63;
  // recv reduce (wave per token), result kept in a register for phase 2
  float recv;
  {
    int t = t0 + wv, b = t >> 10, k = t & 1023;
    const float* rp = recv_part + ((size_t)(b*1024 + k))*128;
    float s = rp[lane] + rp[lane + 64];
    #pragma unroll
    for (int off = 32; off; off >>= 1) s += __shfl_xor(s, off);
    recv = s * (1.f/8192.f);     // /(H=8 * T=1024)
  }
  ld2[lane*8 + wv] = ln1[(t0 + wv)*64 + lane];
  {
    const float4* src = (const float4*)(params + P_W1T);
    float4* dst = (float4*)w;
    #pragma unroll
    for (int i = tid; i < 4096; i += 512) dst[i] = src[i];
  }
  __syncthreads();
  // phase 1: hidden = gelu(ln1 @ W1^T + b1); half-block g handles tokens g*4..g*4+3
  {
    int g = tid >> 8, u = tid & 255;
    float a0, a1, a2, a3;
    a0 = a1 = a2 = a3 = params[P_B1 + u];
    #pragma unroll 8
    for (int j = 0; j < 64; ++j) {
      float wj = w[j*256 + u];                     // stride-1 LDS
      float4 xj = *(const float4*)(ld2 + j*8 + g*4); // broadcast b128
      a0 += wj*xj.x; a1 += wj*xj.y; a2 += wj*xj.z; a3 += wj*xj.w;
    }
    float av[4] = {a0, a1, a2, a3};
    #pragma unroll
    for (int t2 = 0; t2 < 4; ++t2) {
      float v = av[t2];
      float u2 = 1.5957691f*v + 0.07135481f*v*v*v;   // tanh-GELU sigmoid form
      hbuf[(g*4 + t2)*256 + u] = v * rcpf(1.f + __expf(-u2));
    }
  }
  __syncthreads();
  // re-stage W2T over the same arena
  {
    const float4* src = (const float4*)(params + P_W2T);
    float4* dst = (float4*)w;
    #pragma unroll
    for (int i = tid; i < 4096; i += 512) dst[i] = src[i];
  }
  __syncthreads();
  // phase 2: y = hidden @ W2^T + b2 (wave per token); LN2; gate; un-block
  int j = lane;
  int t = t0 + wv, b = t >> 10;
  float y = params[P_B2 + j];
  const float* hb = hbuf + wv*256;
  #pragma unroll 8
  for (int k = 0; k < 256; ++k) y += w[k*64 + j] * hb[k];   // stride-1 LDS + broadcast
  float z = ld2[j*8 + wv] + y;
  float s = z, s2 = z*z;
  #pragma unroll
  for (int off = 32; off; off >>= 1) { s += __shfl_xor(s, off); s2 += __shfl_xor(s2, off); }
  float mu  = s  * (1.f/64.f);
  float var = s2 * (1.f/64.f) - mu*mu;
  float y2 = (z - mu) * rsqrtf(var + 1e-5f) * params[P_G2 + j] + params[P_BE2 + j];
  bool is64 = ((tok32[1] | tok32[3] | tok32[5] | tok32[7]) == 0);
  int tok = is64 ? tok32[t*2] : tok32[t];
  int i = j >> 2, e = j & 3;
  float sv = ldf<ISBF>(sens_emb, tok*16 + i) + recv * params[P_SAL + i];
  float sg = rcpf(1.f + __expf(-sv));
  float blk = blocks[t*64 + j];
  float nb = blk + (y2 - blk) * sg;
  int rb = i >> 2, cb = i & 3, r = e >> 1, c = e & 1;
  int oidx = t*64 + (rb*2 + r)*8 + cb*2 + c;
  if (ISBF) ((__hip_bfloat16*)out)[oidx] = __float2bfloat16(nb);
  else      ((float*)out)[oidx] = nb;
}

extern "C" void kernel_launch(void* const* d_in, const int* in_sizes, int n_in,
                              void* d_out, int out_size, void* d_ws, size_t ws_size,
                              hipStream_t stream) {
  const void* M        = d_in[0];
  const int*  tok      = (const int*)d_in[1];
  const void* Wqkv_blk = d_in[2];
  const void* bqkv_blk = d_in[3];
  const void* Wo_blk   = d_in[4];
  const void* bo_blk   = d_in[5];
  const void* Wqkv_c   = d_in[6];
  const void* bqkv_c   = d_in[7];
  const void* Wo_c     = d_in[8];
  const void* bo_c     = d_in[9];
  const void* W1       = d_in[10];
  const void* b1       = d_in[11];
  const void* W2       = d_in[12];
  const void* b2       = d_in[13];
  const void* g1       = d_in[14];
  const void* be1      = d_in[15];
  const void* g2i      = d_in[16];
  const void* be2      = d_in[17];
  const void* sens_emb = d_in[18];
  const void* sens_al  = d_in[19];

  float* ws = (float*)d_ws;
  float* blocks    = ws + OFF_BLOCKS;
  float* qkv_blk   = ws + OFF_QKVB;
  float* recv_part = ws + OFF_RECVP;   // aliases qkv_blk (dead after k_blk_part)
  float* all_blk   = ws + OFF_ALLB;
  float* qkv_c     = ws + OFF_QKVC;
  float* l_c       = ws + OFF_LC;
  float* acc_c     = ws + OFF_ACCC;
  float* ln1       = ws + OFF_LN1;
  float* params    = ws + OFF_PARAMS;

  k_prep2<true ><<<272, 256, 0, stream>>>(M, Wqkv_blk, bqkv_blk, W1, W2, Wqkv_c, Wo_c,
                                          Wo_blk, bo_blk, bqkv_c, bo_c, g1, be1, b1, b2,
                                          g2i, be2, sens_al, blocks, qkv_blk, params);
  k_prep2<false><<<272, 256, 0, stream>>>(M, Wqkv_blk, bqkv_blk, W1, W2, Wqkv_c, Wo_c,
                                          Wo_blk, bo_blk, bqkv_c, bo_c, g1, be1, b1, b2,
                                          g2i, be2, sens_al, blocks, qkv_blk, params);
  k_blk_part<<<512, 512, 0, stream>>>(qkv_blk, params, all_blk);
  k_qkv_c2<<<1024, 256, 0, stream>>>(all_blk, params, qkv_c);
  k_cross6<<<512, 512, 0, stream>>>(qkv_c, l_c, acc_c, recv_part);
  k_fin<<<1024, 256, 0, stream>>>(all_blk, acc_c, params, ln1);
  k_ffn_out2<true ><<<512, 512, 0, stream>>>(M, ln1, params, blocks, tok, recv_part,
                                             sens_emb, (void*)d_out);
  k_ffn_out2<false><<<512, 512, 0, stream>>>(M, ln1, params, blocks, tok, recv_part,
                                             sens_emb, (void*)d_out);
}